// Round 1
// baseline (507.131 us; speedup 1.0000x reference)
//
#include <hip/hip_runtime.h>

#define B_   16
#define C_   512
#define HW_  1024
#define S_   77
#define CTX_ 768
#define HEADS_ 8
#define D_   64
#define G_   8
#define EPS_ 1e-5f

typedef unsigned short u16;
typedef __attribute__((ext_vector_type(8))) short bfx8;   // 8 bf16 (4 VGPRs) MFMA A/B frag
typedef __attribute__((ext_vector_type(4))) float fx4;    // MFMA C/D frag

__device__ inline u16 f2bf(float f) {
  union { float f; unsigned u; } v; v.f = f;
  unsigned u = v.u;
  unsigned r = (u + 0x7FFFu + ((u >> 16) & 1u)) >> 16;
  return (u16)r;
}
__device__ inline float bf2f(u16 h) {
  union { unsigned u; float f; } v; v.u = ((unsigned)h) << 16;
  return v.f;
}

// ---------------- cast f32 -> bf16 (grid-stride by 4) ----------------
__global__ __launch_bounds__(256) void cast_kernel(const float* __restrict__ in,
                                                   u16* __restrict__ out, int n) {
  int i = (blockIdx.x * 256 + threadIdx.x) * 4;
  if (i >= n) return;
  float4 v = *(const float4*)(in + i);
  unsigned lo = (unsigned)f2bf(v.x) | ((unsigned)f2bf(v.y) << 16);
  unsigned hi = (unsigned)f2bf(v.z) | ((unsigned)f2bf(v.w) << 16);
  uint2 o; o.x = lo; o.y = hi;
  *(uint2*)(out + i) = o;
}

// ---------------- GroupNorm: one block per (batch, group) ----------------
__global__ __launch_bounds__(256) void gn_kernel(const float* __restrict__ x,
                                                 const float* __restrict__ w,
                                                 const float* __restrict__ b,
                                                 u16* __restrict__ h) {
  const int CPG = C_ / G_;                 // 64
  int bg = blockIdx.x;
  int batch = bg >> 3, g = bg & 7;
  size_t base = ((size_t)batch * C_ + (size_t)g * CPG) * HW_;
  const float4* x4 = (const float4*)(x + base);
  const int N4 = CPG * HW_ / 4;            // 16384 float4s
  float s = 0.f, ss = 0.f;
  for (int i = threadIdx.x; i < N4; i += 256) {
    float4 v = x4[i];
    s  += v.x + v.y + v.z + v.w;
    ss += v.x*v.x + v.y*v.y + v.z*v.z + v.w*v.w;
  }
  #pragma unroll
  for (int off = 32; off; off >>= 1) {
    s  += __shfl_down(s, off);
    ss += __shfl_down(ss, off);
  }
  __shared__ float rs[4], rss[4], mr[2];
  int wid = threadIdx.x >> 6;
  if ((threadIdx.x & 63) == 0) { rs[wid] = s; rss[wid] = ss; }
  __syncthreads();
  if (threadIdx.x == 0) {
    float S0 = rs[0] + rs[1] + rs[2] + rs[3];
    float S1 = rss[0] + rss[1] + rss[2] + rss[3];
    const float invN = 1.0f / (float)(CPG * HW_);
    float m = S0 * invN;
    float var = S1 * invN - m * m;
    mr[0] = m; mr[1] = rsqrtf(var + EPS_);
  }
  __syncthreads();
  float m = mr[0], r = mr[1];
  for (int i = threadIdx.x; i < N4; i += 256) {
    float4 v = x4[i];
    int c = g * CPG + (i >> 8);            // i / 256 (256 float4 per channel row)
    float wc = w[c] * r;
    float bc = b[c] - m * wc;
    unsigned lo = (unsigned)f2bf(v.x * wc + bc) | ((unsigned)f2bf(v.y * wc + bc) << 16);
    unsigned hi = (unsigned)f2bf(v.z * wc + bc) | ((unsigned)f2bf(v.w * wc + bc) << 16);
    uint2 o; o.x = lo; o.y = hi;
    *(uint2*)(h + base + (size_t)i * 4) = o;
  }
}

// ---------------- bf16 MFMA GEMM: out[b][m][n] = A[m,:] . B[b][:,n] + bias ----------------
// A: [M,K] bf16 row-major (weights, shared over batch)
// B: BNMAJ ? [N,K] per batch (context)  :  [K,N] per batch (h / attn-out)
// out: f32 (optional residual add) or bf16
template<bool BNMAJ, bool RESID, bool OUTBF>
__global__ __launch_bounds__(256) void gemm_kernel(
    const u16* __restrict__ A, const u16* __restrict__ Bg,
    const float* __restrict__ bias, const float* __restrict__ resid,
    float* __restrict__ outf, u16* __restrict__ outb,
    int M, int N, int K, int ldb, int ldc,
    size_t bstrideB, size_t bstrideO)
{
  __shared__ u16 As[64][40];   // [m][k], +8 pad
  __shared__ u16 Bs[64][40];   // [n][k], +8 pad
  int tid = threadIdx.x;
  int batch = blockIdx.z;
  int n0 = blockIdx.x * 64, m0 = blockIdx.y * 64;
  const u16* Bp = Bg + (size_t)batch * bstrideB;
  int wid = tid >> 6, lane = tid & 63;
  int wr = wid >> 1, wc = wid & 1;
  int fcol = lane & 15;
  int fk8  = (lane >> 4) * 8;
  int frow = (lane >> 4) * 4;
  fx4 acc[2][2];
  #pragma unroll
  for (int i = 0; i < 2; ++i)
    #pragma unroll
    for (int j = 0; j < 2; ++j) acc[i][j] = (fx4){0.f, 0.f, 0.f, 0.f};

  int arow = tid >> 2, akg = (tid & 3) * 8;   // A tile: 64 rows x 32 k
  int bkrow = tid >> 3, bng = (tid & 7) * 8;  // KMAJ B tile: 32 k x 64 n

  for (int k0 = 0; k0 < K; k0 += 32) {
    uint4 av = *(const uint4*)(A + (size_t)(m0 + arow) * K + k0 + akg);
    uint4 bv;
    if (BNMAJ) {
      int n = n0 + arow;
      bv.x = bv.y = bv.z = bv.w = 0u;
      if (n < N) bv = *(const uint4*)(Bp + (size_t)n * ldb + k0 + akg);
    } else {
      bv = *(const uint4*)(Bp + (size_t)(k0 + bkrow) * ldb + n0 + bng);
    }
    *(uint4*)&As[arow][akg] = av;
    if (BNMAJ) {
      *(uint4*)&Bs[arow][akg] = bv;
    } else {
      u16* pv = (u16*)&bv;
      #pragma unroll
      for (int j = 0; j < 8; ++j) Bs[bng + j][bkrow] = pv[j];
    }
    __syncthreads();
    bfx8 a0 = *(const bfx8*)&As[wr * 32 + fcol][fk8];
    bfx8 a1 = *(const bfx8*)&As[wr * 32 + 16 + fcol][fk8];
    bfx8 b0 = *(const bfx8*)&Bs[wc * 32 + fcol][fk8];
    bfx8 b1 = *(const bfx8*)&Bs[wc * 32 + 16 + fcol][fk8];
    acc[0][0] = __builtin_amdgcn_mfma_f32_16x16x32_bf16(a0, b0, acc[0][0], 0, 0, 0);
    acc[0][1] = __builtin_amdgcn_mfma_f32_16x16x32_bf16(a0, b1, acc[0][1], 0, 0, 0);
    acc[1][0] = __builtin_amdgcn_mfma_f32_16x16x32_bf16(a1, b0, acc[1][0], 0, 0, 0);
    acc[1][1] = __builtin_amdgcn_mfma_f32_16x16x32_bf16(a1, b1, acc[1][1], 0, 0, 0);
    __syncthreads();
  }
  #pragma unroll
  for (int mi = 0; mi < 2; ++mi)
    #pragma unroll
    for (int ni = 0; ni < 2; ++ni) {
      int n = n0 + wc * 32 + ni * 16 + fcol;
      if (n < N) {
        int mbase = m0 + wr * 32 + mi * 16 + frow;
        #pragma unroll
        for (int r = 0; r < 4; ++r) {
          int m = mbase + r;
          float v = acc[mi][ni][r] + bias[m];
          size_t idx = (size_t)batch * bstrideO + (size_t)m * ldc + n;
          if (RESID) v += resid[idx];
          if (OUTBF) outb[idx] = f2bf(v);
          else       outf[idx] = v;
        }
      }
    }
}

// ---------------- attention: per (b, head, 128-col chunk) ----------------
__global__ __launch_bounds__(256) void attn_kernel(const u16* __restrict__ q,
                                                   const float* __restrict__ kvt,
                                                   u16* __restrict__ ao) {
  int n0 = blockIdx.x * 128;
  int head = blockIdx.y;
  int batch = blockIdx.z;
  __shared__ u16 qs[64][128];       // [d][j]
  __shared__ float ks[77][65];      // [s][d] padded
  __shared__ float vs[77][65];
  __shared__ u16 p_all[128][81];    // [j][s] bf16 softmax weights
  int tid = threadIdx.x;
  const u16* qp = q + ((size_t)batch * C_ + (size_t)head * 64) * HW_ + n0;
  for (int i = tid; i < 64 * 16; i += 256) {
    int d = i >> 4, c8 = (i & 15) * 8;
    *(uint4*)&qs[d][c8] = *(const uint4*)(qp + (size_t)d * HW_ + c8);
  }
  const float* kp = kvt + ((size_t)batch * 1024 + (size_t)head * 64) * 80;
  const float* vp = kvt + ((size_t)batch * 1024 + 512 + (size_t)head * 64) * 80;
  for (int i = tid; i < 64 * 80; i += 256) {
    int d = i / 80, s = i - d * 80;
    if (s < S_) {
      ks[s][d] = kp[(size_t)d * 80 + s];
      vs[s][d] = vp[(size_t)d * 80 + s];
    }
  }
  __syncthreads();
  int wid = tid >> 6, lane = tid & 63;
  bool has2 = lane < (S_ - 64);      // lanes 0..12 own s = lane+64
  for (int jj = 0; jj < 32; ++jj) {
    int j = wid * 32 + jj;
    float sc1 = 0.f, sc2 = 0.f;
    #pragma unroll 8
    for (int d = 0; d < 64; ++d) {
      float qd = bf2f(qs[d][j]);
      sc1 += qd * ks[lane][d];
      if (has2) sc2 += qd * ks[lane + 64][d];
    }
    sc1 *= 0.125f;
    sc2 = has2 ? sc2 * 0.125f : -1e30f;
    float mx = fmaxf(sc1, sc2);
    #pragma unroll
    for (int off = 32; off; off >>= 1) mx = fmaxf(mx, __shfl_xor(mx, off));
    float e1 = __expf(sc1 - mx);
    float e2 = has2 ? __expf(sc2 - mx) : 0.f;
    float sm = e1 + e2;
    #pragma unroll
    for (int off = 32; off; off >>= 1) sm += __shfl_xor(sm, off);
    float inv = 1.0f / sm;
    p_all[j][lane] = f2bf(e1 * inv);
    if (has2) p_all[j][lane + 64] = f2bf(e2 * inv);
  }
  __syncthreads();
  {
    int j = tid & 127, hf = tid >> 7;
    float o[32];
    #pragma unroll
    for (int d = 0; d < 32; ++d) o[d] = 0.f;
    for (int s = 0; s < S_; ++s) {
      float pv = bf2f(p_all[j][s]);
      #pragma unroll
      for (int d = 0; d < 32; ++d) o[d] += pv * vs[s][hf * 32 + d];
    }
    u16* aop = ao + ((size_t)batch * C_ + (size_t)head * 64 + (size_t)hf * 32) * HW_ + n0 + j;
    #pragma unroll
    for (int d = 0; d < 32; ++d) aop[(size_t)d * HW_] = f2bf(o[d]);
  }
}

extern "C" void kernel_launch(void* const* d_in, const int* in_sizes, int n_in,
                              void* d_out, int out_size, void* d_ws, size_t ws_size,
                              hipStream_t stream) {
  const float* x      = (const float*)d_in[0];
  const float* ctx    = (const float*)d_in[1];
  const float* gn_w   = (const float*)d_in[2];
  const float* gn_b   = (const float*)d_in[3];
  const float* q_w    = (const float*)d_in[4];
  const float* q_b    = (const float*)d_in[5];
  const float* kv_w   = (const float*)d_in[6];
  const float* kv_b   = (const float*)d_in[7];
  const float* proj_w = (const float*)d_in[8];
  const float* proj_b = (const float*)d_in[9];
  float* out = (float*)d_out;

  u16* p = (u16*)d_ws;
  u16* qw_bf  = p; p += 262144;        // 512*512
  u16* kvw_bf = p; p += 786432;        // 1024*768
  u16* pjw_bf = p; p += 262144;        // 512*512
  u16* ctx_bf = p; p += 946176;        // 16*77*768
  u16* h_bf   = p; p += 8388608;       // 16*512*1024
  u16* q_bf   = p; p += 8388608;
  u16* ao_bf  = p; p += 8388608;
  float* kv_t = (float*)p;             // 16*1024*80 f32 (padded S)

  cast_kernel<<<262144 / 1024, 256, 0, stream>>>(q_w,    qw_bf,  262144);
  cast_kernel<<<786432 / 1024, 256, 0, stream>>>(kv_w,   kvw_bf, 786432);
  cast_kernel<<<262144 / 1024, 256, 0, stream>>>(proj_w, pjw_bf, 262144);
  cast_kernel<<<946176 / 1024, 256, 0, stream>>>(ctx,    ctx_bf, 946176);

  gn_kernel<<<B_ * G_, 256, 0, stream>>>(x, gn_w, gn_b, h_bf);

  // KV: M=1024 (o2), N=77 (s), K=768; B = context [s][c] per batch (N-major)
  gemm_kernel<true, false, false><<<dim3(2, 16, B_), 256, 0, stream>>>(
      kvw_bf, ctx_bf, kv_b, nullptr, kv_t, nullptr,
      1024, 77, 768, 768, 80, (size_t)77 * 768, (size_t)1024 * 80);

  // Q: M=512, N=1024, K=512; B = h [c][n] per batch (K-major); bf16 out
  gemm_kernel<false, false, true><<<dim3(16, 8, B_), 256, 0, stream>>>(
      qw_bf, h_bf, q_b, nullptr, nullptr, q_bf,
      512, 1024, 512, 1024, 1024, (size_t)512 * 1024, (size_t)512 * 1024);

  attn_kernel<<<dim3(8, 8, B_), 256, 0, stream>>>(q_bf, kv_t, ao_bf);

  // proj: f32 out + residual x
  gemm_kernel<false, true, false><<<dim3(16, 8, B_), 256, 0, stream>>>(
      pjw_bf, ao_bf, proj_b, x, out, nullptr,
      512, 1024, 512, 1024, 1024, (size_t)512 * 1024, (size_t)512 * 1024);
}

// Round 2
// 200.779 us; speedup vs baseline: 2.5258x; 2.5258x over previous
//
#include <hip/hip_runtime.h>

#define B_   16
#define C_   512
#define HW_  1024
#define S_   77
#define CTX_ 768
#define HEADS_ 8
#define D_   64
#define G_   8
#define EPS_ 1e-5f

typedef unsigned short u16;
typedef __attribute__((ext_vector_type(8))) short bfx8;   // 8 bf16 (4 VGPRs) MFMA A/B frag
typedef __attribute__((ext_vector_type(4))) float fx4;    // MFMA C/D frag

__device__ inline u16 f2bf(float f) {
  union { float f; unsigned u; } v; v.f = f;
  unsigned u = v.u;
  unsigned r = (u + 0x7FFFu + ((u >> 16) & 1u)) >> 16;
  return (u16)r;
}
__device__ inline float bf2f(u16 h) {
  union { unsigned u; float f; } v; v.u = ((unsigned)h) << 16;
  return v.f;
}

// ---------------- cast f32 -> bf16 (grid-stride by 4) ----------------
__global__ __launch_bounds__(256) void cast_kernel(const float* __restrict__ in,
                                                   u16* __restrict__ out, int n) {
  int i = (blockIdx.x * 256 + threadIdx.x) * 4;
  if (i >= n) return;
  float4 v = *(const float4*)(in + i);
  unsigned lo = (unsigned)f2bf(v.x) | ((unsigned)f2bf(v.y) << 16);
  unsigned hi = (unsigned)f2bf(v.z) | ((unsigned)f2bf(v.w) << 16);
  uint2 o; o.x = lo; o.y = hi;
  *(uint2*)(out + i) = o;
}

// ---------------- GroupNorm: one block per (batch, group) ----------------
__global__ __launch_bounds__(256) void gn_kernel(const float* __restrict__ x,
                                                 const float* __restrict__ w,
                                                 const float* __restrict__ b,
                                                 u16* __restrict__ h) {
  const int CPG = C_ / G_;                 // 64
  int bg = blockIdx.x;
  int batch = bg >> 3, g = bg & 7;
  size_t base = ((size_t)batch * C_ + (size_t)g * CPG) * HW_;
  const float4* x4 = (const float4*)(x + base);
  const int N4 = CPG * HW_ / 4;            // 16384 float4s
  float s = 0.f, ss = 0.f;
  for (int i = threadIdx.x; i < N4; i += 256) {
    float4 v = x4[i];
    s  += v.x + v.y + v.z + v.w;
    ss += v.x*v.x + v.y*v.y + v.z*v.z + v.w*v.w;
  }
  #pragma unroll
  for (int off = 32; off; off >>= 1) {
    s  += __shfl_down(s, off);
    ss += __shfl_down(ss, off);
  }
  __shared__ float rs[4], rss[4], mr[2];
  int wid = threadIdx.x >> 6;
  if ((threadIdx.x & 63) == 0) { rs[wid] = s; rss[wid] = ss; }
  __syncthreads();
  if (threadIdx.x == 0) {
    float S0 = rs[0] + rs[1] + rs[2] + rs[3];
    float S1 = rss[0] + rss[1] + rss[2] + rss[3];
    const float invN = 1.0f / (float)(CPG * HW_);
    float m = S0 * invN;
    float var = S1 * invN - m * m;
    mr[0] = m; mr[1] = rsqrtf(var + EPS_);
  }
  __syncthreads();
  float m = mr[0], r = mr[1];
  for (int i = threadIdx.x; i < N4; i += 256) {
    float4 v = x4[i];
    int c = g * CPG + (i >> 8);            // i / 256 (256 float4 per channel row)
    float wc = w[c] * r;
    float bc = b[c] - m * wc;
    unsigned lo = (unsigned)f2bf(v.x * wc + bc) | ((unsigned)f2bf(v.y * wc + bc) << 16);
    unsigned hi = (unsigned)f2bf(v.z * wc + bc) | ((unsigned)f2bf(v.w * wc + bc) << 16);
    uint2 o; o.x = lo; o.y = hi;
    *(uint2*)(h + base + (size_t)i * 4) = o;
  }
}

// ---------------- bf16 MFMA GEMM: out[b][m][n] = A[m,:] . B[b][:,n] + bias ----------------
template<bool BNMAJ, bool RESID, bool OUTBF>
__global__ __launch_bounds__(256) void gemm_kernel(
    const u16* __restrict__ A, const u16* __restrict__ Bg,
    const float* __restrict__ bias, const float* __restrict__ resid,
    float* __restrict__ outf, u16* __restrict__ outb,
    int M, int N, int K, int ldb, int ldc,
    size_t bstrideB, size_t bstrideO)
{
  __shared__ u16 As[64][40];   // [m][k], +8 pad
  __shared__ u16 Bs[64][40];   // [n][k], +8 pad
  int tid = threadIdx.x;
  int batch = blockIdx.z;
  int n0 = blockIdx.x * 64, m0 = blockIdx.y * 64;
  const u16* Bp = Bg + (size_t)batch * bstrideB;
  int wid = tid >> 6, lane = tid & 63;
  int wr = wid >> 1, wc = wid & 1;
  int fcol = lane & 15;
  int fk8  = (lane >> 4) * 8;
  int frow = (lane >> 4) * 4;
  fx4 acc[2][2];
  #pragma unroll
  for (int i = 0; i < 2; ++i)
    #pragma unroll
    for (int j = 0; j < 2; ++j) acc[i][j] = (fx4){0.f, 0.f, 0.f, 0.f};

  int arow = tid >> 2, akg = (tid & 3) * 8;   // A tile: 64 rows x 32 k
  int bkrow = tid >> 3, bng = (tid & 7) * 8;  // KMAJ B tile: 32 k x 64 n

  for (int k0 = 0; k0 < K; k0 += 32) {
    uint4 av = *(const uint4*)(A + (size_t)(m0 + arow) * K + k0 + akg);
    uint4 bv;
    if (BNMAJ) {
      int n = n0 + arow;
      bv.x = bv.y = bv.z = bv.w = 0u;
      if (n < N) bv = *(const uint4*)(Bp + (size_t)n * ldb + k0 + akg);
    } else {
      bv = *(const uint4*)(Bp + (size_t)(k0 + bkrow) * ldb + n0 + bng);
    }
    *(uint4*)&As[arow][akg] = av;
    if (BNMAJ) {
      *(uint4*)&Bs[arow][akg] = bv;
    } else {
      u16* pv = (u16*)&bv;
      #pragma unroll
      for (int j = 0; j < 8; ++j) Bs[bng + j][bkrow] = pv[j];
    }
    __syncthreads();
    bfx8 a0 = *(const bfx8*)&As[wr * 32 + fcol][fk8];
    bfx8 a1 = *(const bfx8*)&As[wr * 32 + 16 + fcol][fk8];
    bfx8 b0 = *(const bfx8*)&Bs[wc * 32 + fcol][fk8];
    bfx8 b1 = *(const bfx8*)&Bs[wc * 32 + 16 + fcol][fk8];
    acc[0][0] = __builtin_amdgcn_mfma_f32_16x16x32_bf16(a0, b0, acc[0][0], 0, 0, 0);
    acc[0][1] = __builtin_amdgcn_mfma_f32_16x16x32_bf16(a0, b1, acc[0][1], 0, 0, 0);
    acc[1][0] = __builtin_amdgcn_mfma_f32_16x16x32_bf16(a1, b0, acc[1][0], 0, 0, 0);
    acc[1][1] = __builtin_amdgcn_mfma_f32_16x16x32_bf16(a1, b1, acc[1][1], 0, 0, 0);
    __syncthreads();
  }
  #pragma unroll
  for (int mi = 0; mi < 2; ++mi)
    #pragma unroll
    for (int ni = 0; ni < 2; ++ni) {
      int n = n0 + wc * 32 + ni * 16 + fcol;
      if (n < N) {
        int mbase = m0 + wr * 32 + mi * 16 + frow;
        #pragma unroll
        for (int r = 0; r < 4; ++r) {
          int m = mbase + r;
          float v = acc[mi][ni][r] + bias[m];
          size_t idx = (size_t)batch * bstrideO + (size_t)m * ldc + n;
          if (RESID) v += resid[idx];
          if (OUTBF) outb[idx] = f2bf(v);
          else       outf[idx] = v;
        }
      }
    }
}

// ---------------- MFMA attention: one block per (b, head, 128-query chunk) ----------------
// q_bf:  [b][c=h*64+d][n]  bf16 (d-major)
// kv_bf: [b][o][s(pad80)]  bf16, o<512: K rows (h*64+d), o>=512: V rows
// ao:    [b][c=h*64+d][n]  bf16
__global__ __launch_bounds__(256) void attn_kernel(const u16* __restrict__ q,
                                                   const u16* __restrict__ kv,
                                                   u16* __restrict__ ao) {
  __shared__ u16 QOs[128 * 72];      // Qs view: [128 q][72 (d+pad)]; Os view: [64 d][136 (q+pad)]
  __shared__ u16 Ks[80][72];         // [s][d+pad]
  __shared__ u16 Vs[64][104];        // [d][s+pad], s in [0,96), zero-padded past 77
  __shared__ u16 Ps[128][104];       // [q][s+pad] bf16 softmax weights, zero-padded past 77
  u16 (*Qs)[72]  = (u16(*)[72])QOs;
  u16 (*Os)[136] = (u16(*)[136])QOs;

  int tid = threadIdx.x;
  int n0 = blockIdx.x * 128;
  int head = blockIdx.y;
  int batch = blockIdx.z;

  const u16* qp = q + ((size_t)batch * C_ + (size_t)head * 64) * HW_ + n0;
  const u16* kp = kv + ((size_t)batch * 1024 + (size_t)head * 64) * 80;
  const u16* vp = kv + ((size_t)batch * 1024 + 512 + (size_t)head * 64) * 80;

  // ---- stage Q (transpose [d][n] -> [q][d]) ----
  for (int i = tid; i < 64 * 16; i += 256) {
    int d = i >> 4, j8 = (i & 15) * 8;
    uint4 v = *(const uint4*)(qp + (size_t)d * HW_ + j8);
    const u16* pv = (const u16*)&v;
    #pragma unroll
    for (int jj = 0; jj < 8; ++jj) Qs[j8 + jj][d] = pv[jj];
  }
  // ---- stage K (transpose [d][s] -> [s][d]), zero s>=77 ----
  for (int i = tid; i < 64 * 80; i += 256) {
    int d = i / 80, s = i - d * 80;
    Ks[s][d] = (s < S_) ? kp[(size_t)d * 80 + s] : (u16)0;
  }
  // ---- stage V direct [d][s], zero s>=77 ----
  for (int i = tid; i < 64 * 96; i += 256) {
    int d = i / 96, s = i - d * 96;
    Vs[d][s] = (s < S_) ? vp[(size_t)d * 80 + s] : (u16)0;
  }
  // ---- zero P (pad cols must be 0 for PV K=96) ----
  {
    uint4* pz = (uint4*)&Ps[0][0];
    for (int i = tid; i < (128 * 104) / 8; i += 256) pz[i] = (uint4){0u, 0u, 0u, 0u};
  }
  __syncthreads();

  int wid = tid >> 6, l = tid & 63;
  int lr = l & 15;          // frag row/col
  int lg = l >> 4;          // k-group
  int qbase = wid * 32;

  // ---- scores + softmax + P ----
  #pragma unroll
  for (int qt = 0; qt < 2; ++qt) {
    fx4 sc[5];
    #pragma unroll
    for (int t = 0; t < 5; ++t) sc[t] = (fx4){0.f, 0.f, 0.f, 0.f};
    #pragma unroll
    for (int ks = 0; ks < 2; ++ks) {
      bfx8 a = *(const bfx8*)&Qs[qbase + qt * 16 + lr][ks * 32 + lg * 8];
      #pragma unroll
      for (int t = 0; t < 5; ++t) {
        bfx8 b = *(const bfx8*)&Ks[t * 16 + lr][ks * 32 + lg * 8];
        sc[t] = __builtin_amdgcn_mfma_f32_16x16x32_bf16(a, b, sc[t], 0, 0, 0);
      }
    }
    // mask + scale
    #pragma unroll
    for (int t = 0; t < 5; ++t) {
      bool valid = (t * 16 + lr) < S_;
      #pragma unroll
      for (int r = 0; r < 4; ++r)
        sc[t][r] = valid ? sc[t][r] * 0.125f : -1e30f;
    }
    // rowwise max (over 5 tiles, then across the 16 lanes of this row-group)
    fx4 mx = sc[0];
    #pragma unroll
    for (int t = 1; t < 5; ++t)
      #pragma unroll
      for (int r = 0; r < 4; ++r) mx[r] = fmaxf(mx[r], sc[t][r]);
    #pragma unroll
    for (int off = 1; off < 16; off <<= 1)
      #pragma unroll
      for (int r = 0; r < 4; ++r) mx[r] = fmaxf(mx[r], __shfl_xor(mx[r], off));
    // exp + sum
    fx4 sm = (fx4){0.f, 0.f, 0.f, 0.f};
    #pragma unroll
    for (int t = 0; t < 5; ++t)
      #pragma unroll
      for (int r = 0; r < 4; ++r) {
        float e = __expf(sc[t][r] - mx[r]);
        sc[t][r] = e; sm[r] += e;
      }
    #pragma unroll
    for (int off = 1; off < 16; off <<= 1)
      #pragma unroll
      for (int r = 0; r < 4; ++r) sm[r] += __shfl_xor(sm[r], off);
    fx4 inv;
    #pragma unroll
    for (int r = 0; r < 4; ++r) inv[r] = 1.0f / sm[r];
    // scatter P (bf16); masked entries are exp(-huge)=0 so pad stays 0
    #pragma unroll
    for (int t = 0; t < 5; ++t)
      #pragma unroll
      for (int r = 0; r < 4; ++r)
        Ps[qbase + qt * 16 + lg * 4 + r][t * 16 + lr] = f2bf(sc[t][r] * inv[r]);
  }
  __syncthreads();   // all waves done reading Qs (Os aliases it); P visible to own wave

  // ---- PV ----
  #pragma unroll
  for (int qt = 0; qt < 2; ++qt) {
    fx4 o[4];
    #pragma unroll
    for (int dt = 0; dt < 4; ++dt) o[dt] = (fx4){0.f, 0.f, 0.f, 0.f};
    #pragma unroll
    for (int ks = 0; ks < 3; ++ks) {
      bfx8 a = *(const bfx8*)&Ps[qbase + qt * 16 + lr][ks * 32 + lg * 8];
      #pragma unroll
      for (int dt = 0; dt < 4; ++dt) {
        bfx8 b = *(const bfx8*)&Vs[dt * 16 + lr][ks * 32 + lg * 8];
        o[dt] = __builtin_amdgcn_mfma_f32_16x16x32_bf16(a, b, o[dt], 0, 0, 0);
      }
    }
    // write Os[d][q]: 4 consecutive q per lane -> packed uint2
    #pragma unroll
    for (int dt = 0; dt < 4; ++dt) {
      unsigned lo = (unsigned)f2bf(o[dt][0]) | ((unsigned)f2bf(o[dt][1]) << 16);
      unsigned hi = (unsigned)f2bf(o[dt][2]) | ((unsigned)f2bf(o[dt][3]) << 16);
      uint2 pk; pk.x = lo; pk.y = hi;
      *(uint2*)&Os[dt * 16 + lr][qbase + qt * 16 + lg * 4] = pk;
    }
  }
  __syncthreads();

  // ---- coalesced output ----
  u16* aop = ao + ((size_t)batch * C_ + (size_t)head * 64) * HW_ + n0;
  for (int i = tid; i < 64 * 16; i += 256) {
    int d = i >> 4, part = (i & 15) * 8;
    uint4 v = *(const uint4*)&Os[d][part];
    *(uint4*)(aop + (size_t)d * HW_ + part) = v;
  }
}

extern "C" void kernel_launch(void* const* d_in, const int* in_sizes, int n_in,
                              void* d_out, int out_size, void* d_ws, size_t ws_size,
                              hipStream_t stream) {
  const float* x      = (const float*)d_in[0];
  const float* ctx    = (const float*)d_in[1];
  const float* gn_w   = (const float*)d_in[2];
  const float* gn_b   = (const float*)d_in[3];
  const float* q_w    = (const float*)d_in[4];
  const float* q_b    = (const float*)d_in[5];
  const float* kv_w   = (const float*)d_in[6];
  const float* kv_b   = (const float*)d_in[7];
  const float* proj_w = (const float*)d_in[8];
  const float* proj_b = (const float*)d_in[9];
  float* out = (float*)d_out;

  u16* p = (u16*)d_ws;
  u16* qw_bf  = p; p += 262144;        // 512*512
  u16* kvw_bf = p; p += 786432;        // 1024*768
  u16* pjw_bf = p; p += 262144;        // 512*512
  u16* ctx_bf = p; p += 946176;        // 16*77*768
  u16* h_bf   = p; p += 8388608;       // 16*512*1024
  u16* q_bf   = p; p += 8388608;
  u16* ao_bf  = p; p += 8388608;
  u16* kv_bf  = p; p += 1310720;       // 16*1024*80 bf16 (padded S)

  cast_kernel<<<262144 / 1024, 256, 0, stream>>>(q_w,    qw_bf,  262144);
  cast_kernel<<<786432 / 1024, 256, 0, stream>>>(kv_w,   kvw_bf, 786432);
  cast_kernel<<<262144 / 1024, 256, 0, stream>>>(proj_w, pjw_bf, 262144);
  cast_kernel<<<946176 / 1024, 256, 0, stream>>>(ctx,    ctx_bf, 946176);

  gn_kernel<<<B_ * G_, 256, 0, stream>>>(x, gn_w, gn_b, h_bf);

  // KV: M=1024 (o), N=77 (s), K=768; B = context [s][c] per batch (N-major); bf16 out
  gemm_kernel<true, false, true><<<dim3(2, 16, B_), 256, 0, stream>>>(
      kvw_bf, ctx_bf, kv_b, nullptr, nullptr, kv_bf,
      1024, 77, 768, 768, 80, (size_t)77 * 768, (size_t)1024 * 80);

  // Q: M=512, N=1024, K=512; B = h [c][n] per batch (K-major); bf16 out
  gemm_kernel<false, false, true><<<dim3(16, 8, B_), 256, 0, stream>>>(
      qw_bf, h_bf, q_b, nullptr, nullptr, q_bf,
      512, 1024, 512, 1024, 1024, (size_t)512 * 1024, (size_t)512 * 1024);

  attn_kernel<<<dim3(8, HEADS_, B_), 256, 0, stream>>>(q_bf, kv_bf, ao_bf);

  // proj: f32 out + residual x
  gemm_kernel<false, true, false><<<dim3(16, 8, B_), 256, 0, stream>>>(
      pjw_bf, ao_bf, proj_b, x, out, nullptr,
      512, 1024, 512, 1024, 1024, (size_t)512 * 1024, (size_t)512 * 1024);
}

// Round 4
// 138.910 us; speedup vs baseline: 3.6508x; 1.4454x over previous
//
#include <hip/hip_runtime.h>

#define B_   16
#define C_   512
#define HW_  1024
#define S_   77
#define CTX_ 768
#define HEADS_ 8
#define G_   8
#define EPS_ 1e-5f

typedef unsigned short u16;
typedef unsigned int u32;
typedef __attribute__((ext_vector_type(8))) short bfx8;   // 8 bf16 MFMA A/B frag
typedef __attribute__((ext_vector_type(4))) float fx4;    // MFMA C/D frag

union U2 { u16 h[4]; uint2 v; };

__device__ __forceinline__ u16 f2bf(float f) {
  union { float f; u32 u; } v; v.f = f;
  u32 u = v.u;
  return (u16)((u + 0x7FFFu + ((u >> 16) & 1u)) >> 16);
}

// async global->LDS, 16B per lane (lane-linear LDS dest, per-lane global src)
__device__ __forceinline__ void gload16(const u16* g, u16* l) {
  __builtin_amdgcn_global_load_lds((const __attribute__((address_space(1))) u32*)g,
                                   (__attribute__((address_space(3))) u32*)l, 16, 0, 0);
}

// ---------------- weight cast f32 -> bf16, row-swizzled ----------------
// out[m][k] stored: m*K + (k&~63) + (((k%64)/8 ^ (m&7))*8) + (k&7)
__global__ __launch_bounds__(256) void castw_kernel(const float* __restrict__ in,
                                                    u16* __restrict__ out, int K, int n4) {
  int i = blockIdx.x * 256 + threadIdx.x;
  if (i >= n4) return;
  float4 v = *(const float4*)(in + (size_t)i * 4);
  int K4 = K >> 2;
  int m = i / K4;
  int k = (i - m * K4) * 4;
  int pb = ((k & 63) >> 3) ^ (m & 7);
  size_t dst = (size_t)m * K + (k & ~63) + (pb << 3) + (k & 7);
  U2 pk;
  pk.h[0] = f2bf(v.x); pk.h[1] = f2bf(v.y); pk.h[2] = f2bf(v.z); pk.h[3] = f2bf(v.w);
  *(uint2*)(out + dst) = pk.v;
}

// ---------------- context cast: [b][77][768] f32 -> [b][128pad][768] bf16 swizzled ----------------
__global__ __launch_bounds__(256) void castctx_kernel(const float* __restrict__ in,
                                                      u16* __restrict__ out) {
  int i = blockIdx.x * 256 + threadIdx.x;
  if (i >= 16 * 77 * 192) return;
  int rg = i / 192;
  int k = (i - rg * 192) * 4;
  int b = rg / 77, s = rg - b * 77;
  float4 v = *(const float4*)(in + (size_t)i * 4);
  int pb = ((k & 63) >> 3) ^ (s & 7);
  size_t dst = ((size_t)b * 128 + s) * 768 + (k & ~63) + (pb << 3) + (k & 7);
  U2 pk;
  pk.h[0] = f2bf(v.x); pk.h[1] = f2bf(v.y); pk.h[2] = f2bf(v.z); pk.h[3] = f2bf(v.w);
  *(uint2*)(out + dst) = pk.v;
}

// ---------------- GroupNorm -> h^T [b][n=1024][c=512] bf16 swizzled ----------------
__global__ __launch_bounds__(256) void gn_kernel(const float* __restrict__ x,
                                                 const float* __restrict__ w,
                                                 const float* __restrict__ bgn,
                                                 u16* __restrict__ hT) {
  int bg = blockIdx.x;
  int batch = bg >> 3, g = bg & 7;
  size_t base = ((size_t)batch * C_ + (size_t)g * 64) * HW_;
  const float4* x4 = (const float4*)(x + base);
  const int N4 = 64 * HW_ / 4;
  int t = threadIdx.x;
  float s = 0.f, ss = 0.f;
  for (int i = t; i < N4; i += 256) {
    float4 v = x4[i];
    s  += v.x + v.y + v.z + v.w;
    ss += v.x*v.x + v.y*v.y + v.z*v.z + v.w*v.w;
  }
  #pragma unroll
  for (int off = 32; off; off >>= 1) {
    s  += __shfl_down(s, off);
    ss += __shfl_down(ss, off);
  }
  __shared__ float rs[4], rss[4], mr[2];
  __shared__ u16 T2[128 * 72];
  int wid = t >> 6;
  if ((t & 63) == 0) { rs[wid] = s; rss[wid] = ss; }
  __syncthreads();
  if (t == 0) {
    float S0 = rs[0] + rs[1] + rs[2] + rs[3];
    float S1 = rss[0] + rss[1] + rss[2] + rss[3];
    const float invN = 1.0f / (float)(64 * HW_);
    float m = S0 * invN;
    float var = S1 * invN - m * m;
    mr[0] = m; mr[1] = rsqrtf(var + EPS_);
  }
  __syncthreads();
  float m = mr[0], r = mr[1];
  int c = t >> 2;                        // 0..63
  int cg = g * 64 + c;
  float wc_ = w[cg] * r;
  float bc_ = bgn[cg] - m * wc_;
  for (int nt = 0; nt < 8; ++nt) {
    __syncthreads();
    #pragma unroll
    for (int j4 = 0; j4 < 8; ++j4) {
      int f4 = (t & 3) + j4 * 4;         // 0..31
      float4 v = x4[c * 256 + nt * 32 + f4];
      const float* vp = &v.x;
      int nl = f4 * 4;
      #pragma unroll
      for (int e = 0; e < 4; ++e) {
        int n = nl + e;
        int pb = ((c >> 3) ^ (n & 7));
        T2[n * 72 + (pb << 3) + (c & 7)] = f2bf(vp[e] * wc_ + bc_);
      }
    }
    __syncthreads();
    #pragma unroll
    for (int j = 0; j < 4; ++j) {
      int idx = j * 256 + t;
      int row = idx >> 3, cs = (idx & 7) * 8;
      uint4 vv = *(const uint4*)&T2[row * 72 + cs];
      *(uint4*)(hT + ((size_t)batch * 1024 + nt * 128 + row) * 512 + g * 64 + cs) = vv;
    }
  }
}

// ---------------- m97-style GEMM: D[m][n] = A[b][m][:] . Bw[n][:] + bias[n] ----------------
// A: per-batch activations [Mrows][K] swizzled; Bw: weights [N][K] swizzled.
// EPI 0: q^T bf16 out (rows m, cols n, swizzled). EPI 1: kv split epilogue. EPI 2: f32 out + residual.
template<int EPI>
__global__ __launch_bounds__(256) void gemm2_kernel(
    const u16* __restrict__ A, const u16* __restrict__ Bw,
    const float* __restrict__ bias, const float* __restrict__ resid,
    float* __restrict__ outf, u16* __restrict__ o16a, u16* __restrict__ o16b,
    int K, size_t strideA)
{
  __shared__ u16 As[128 * 64];
  __shared__ u16 Bs[128 * 64];
  int t = threadIdx.x;
  int b = blockIdx.z;
  int n0 = blockIdx.x * 128, m0 = blockIdx.y * 128;
  const u16* aBase = A + (size_t)b * strideA + (size_t)(m0 + (t >> 3)) * K + (t & 7) * 8;
  const u16* bBase = Bw + (size_t)(n0 + (t >> 3)) * K + (t & 7) * 8;
  int wid = t >> 6, l = t & 63;
  int wr = wid >> 1, wc = wid & 1;
  int lr = l & 15, lg = l >> 4;
  fx4 acc[4][4];
  #pragma unroll
  for (int i = 0; i < 4; ++i)
    #pragma unroll
    for (int j = 0; j < 4; ++j) acc[i][j] = (fx4){0.f, 0.f, 0.f, 0.f};

  for (int k0 = 0; k0 < K; k0 += 64) {
    __syncthreads();
    #pragma unroll
    for (int i = 0; i < 4; ++i) {
      gload16(aBase + k0 + (size_t)i * 32 * K, As + i * 2048 + t * 8);
      gload16(bBase + k0 + (size_t)i * 32 * K, Bs + i * 2048 + t * 8);
    }
    __syncthreads();
    #pragma unroll
    for (int kk = 0; kk < 2; ++kk) {
      bfx8 af[4], bf[4];
      int xr = (lr & 7);
      #pragma unroll
      for (int i = 0; i < 4; ++i) {
        int lb = kk * 4 + lg;
        af[i] = *(const bfx8*)&As[(wr * 64 + i * 16 + lr) * 64 + ((lb ^ xr) << 3)];
        bf[i] = *(const bfx8*)&Bs[(wc * 64 + i * 16 + lr) * 64 + ((lb ^ xr) << 3)];
      }
      #pragma unroll
      for (int mi = 0; mi < 4; ++mi)
        #pragma unroll
        for (int ni = 0; ni < 4; ++ni)
          acc[mi][ni] = __builtin_amdgcn_mfma_f32_16x16x32_bf16(af[mi], bf[ni], acc[mi][ni], 0, 0, 0);
    }
  }

  if (EPI == 0) {
    // stage per-wave [64 m][64 c] swizzled tile in LDS, then linear copy to q^T
    __syncthreads();
    u16* T = ((wid & 2) ? Bs : As) + (wid & 1) * 4096;
    #pragma unroll
    for (int mi = 0; mi < 4; ++mi)
      #pragma unroll
      for (int ni = 0; ni < 4; ++ni) {
        int cl = ni * 16 + lr;
        float bb = bias[n0 + wc * 64 + cl];
        #pragma unroll
        for (int r = 0; r < 4; ++r) {
          int ml = mi * 16 + lg * 4 + r;
          int pb = ((cl >> 3) ^ (ml & 7));
          T[ml * 64 + (pb << 3) + (cl & 7)] = f2bf(acc[mi][ni][r] + bb);
        }
      }
    #pragma unroll
    for (int j = 0; j < 8; ++j) {
      int idx = j * 64 + l;
      int row = idx >> 3, cs = (idx & 7) * 8;
      uint4 v = *(const uint4*)&T[row * 64 + cs];
      *(uint4*)(o16a + (size_t)b * 524288 + (size_t)(m0 + wr * 64 + row) * 512
                + n0 + wc * 64 + cs) = v;
    }
  } else if (EPI == 2) {
    float* O = outf + (size_t)b * 524288;
    const float* R = resid + (size_t)b * 524288;
    #pragma unroll
    for (int ni = 0; ni < 4; ++ni) {
      int cc = n0 + wc * 64 + ni * 16 + lr;
      float bb = bias[cc];
      #pragma unroll
      for (int mi = 0; mi < 4; ++mi) {
        size_t off = (size_t)cc * 1024 + m0 + wr * 64 + mi * 16 + lg * 4;
        float4 rv = *(const float4*)(R + off);
        float4 ov;
        ov.x = acc[mi][ni][0] + bb + rv.x;
        ov.y = acc[mi][ni][1] + bb + rv.y;
        ov.z = acc[mi][ni][2] + bb + rv.z;
        ov.w = acc[mi][ni][3] + bb + rv.w;
        *(float4*)(O + off) = ov;
      }
    }
  } else {
    // EPI 1: n<512 -> K^T[s][o] swizzled scatter; n>=512 -> V[d][s] uint2
    #pragma unroll
    for (int ni = 0; ni < 4; ++ni) {
      int o = n0 + wc * 64 + ni * 16 + lr;
      float bb = bias[o];
      #pragma unroll
      for (int mi = 0; mi < 4; ++mi) {
        int sb = wr * 64 + mi * 16 + lg * 4;   // m0 == 0
        if (o < 512) {
          #pragma unroll
          for (int r = 0; r < 4; ++r) {
            int sidx = sb + r;
            if (sidx < 96) {
              int ob = (o & ~63) | (((((o >> 3) & 7) ^ (sidx & 7))) << 3) | (o & 7);
              o16a[(size_t)b * 49152 + (size_t)sidx * 512 + ob] = f2bf(acc[mi][ni][r] + bb);
            }
          }
        } else if (sb < 80) {
          U2 pk;
          #pragma unroll
          for (int r = 0; r < 4; ++r) pk.h[r] = f2bf(acc[mi][ni][r] + bb);
          *(uint2*)(o16b + (size_t)b * 40960 + (size_t)(o - 512) * 80 + sb) = pk.v;
        }
      }
    }
  }
}

// ---------------- MFMA attention: block = (b, head, 128-query chunk) ----------------
// qT: [b][n][512] swizzled; kvK: [b][96][512] swizzled (K^T); kvV: [b][512][80] ([d][s])
// aoT out: [b][n][512] swizzled
__global__ __launch_bounds__(256) void attn_kernel(const u16* __restrict__ qT,
                                                   const u16* __restrict__ kvK,
                                                   const u16* __restrict__ kvV,
                                                   u16* __restrict__ aoT) {
  __shared__ u16 QO[128 * 64];      // Q swizzled; later O^T [q][64 d] swizzled
  __shared__ u16 Ks[96 * 64];       // swizzled [s][d]
  __shared__ u16 Vs[64][104];       // [d][s], s<96 valid (zeros 80..95)
  __shared__ u16 Ps[128][104];      // [q][s] bf16
  int t = threadIdx.x;
  int n0 = blockIdx.x * 128, head = blockIdx.y, b = blockIdx.z;

  const u16* qsrc = qT + (size_t)b * 524288 + (size_t)(n0 + (t >> 3)) * 512 + head * 64 + (t & 7) * 8;
  #pragma unroll
  for (int i = 0; i < 4; ++i) gload16(qsrc + (size_t)i * 32 * 512, QO + i * 2048 + t * 8);
  const u16* ksrc = kvK + (size_t)b * 49152 + (size_t)(t >> 3) * 512 + head * 64 + (t & 7) * 8;
  #pragma unroll
  for (int i = 0; i < 3; ++i) gload16(ksrc + (size_t)i * 32 * 512, Ks + i * 2048 + t * 8);
  const u16* vsrc = kvV + (size_t)b * 40960 + (size_t)head * 64 * 80;
  for (int i = t; i < 640; i += 256) {
    int d = i / 10, sb = i - d * 10;
    *(uint4*)&Vs[d][sb * 8] = *(const uint4*)(vsrc + d * 80 + sb * 8);
  }
  { // zero Vs s in [80,96) and Ps s in [80,96)
    if (t < 128) {
      int d = t >> 1, part = t & 1;
      *(uint4*)&Vs[d][80 + part * 8] = (uint4){0u, 0u, 0u, 0u};
    }
    int row = t >> 1, part = t & 1;
    *(uint4*)&Ps[row][80 + part * 8] = (uint4){0u, 0u, 0u, 0u};
  }
  __syncthreads();

  int wid = t >> 6, l = t & 63;
  int lr = l & 15, lg = l >> 4, xr = lr & 7;
  int qbase = wid * 32;

  // ---- QK^T + softmax + P ----
  #pragma unroll
  for (int qt = 0; qt < 2; ++qt) {
    int qrow = qbase + qt * 16 + lr;
    fx4 sc[5];
    #pragma unroll
    for (int ti = 0; ti < 5; ++ti) sc[ti] = (fx4){0.f, 0.f, 0.f, 0.f};
    #pragma unroll
    for (int ks = 0; ks < 2; ++ks) {
      int lb = ks * 4 + lg;
      bfx8 a = *(const bfx8*)&QO[qrow * 64 + ((lb ^ xr) << 3)];
      #pragma unroll
      for (int ti = 0; ti < 5; ++ti) {
        bfx8 bb = *(const bfx8*)&Ks[(ti * 16 + lr) * 64 + ((lb ^ xr) << 3)];
        sc[ti] = __builtin_amdgcn_mfma_f32_16x16x32_bf16(a, bb, sc[ti], 0, 0, 0);
      }
    }
    #pragma unroll
    for (int ti = 0; ti < 5; ++ti) {
      bool valid = (ti * 16 + lr) < S_;
      #pragma unroll
      for (int r = 0; r < 4; ++r)
        sc[ti][r] = valid ? sc[ti][r] * 0.125f : -1e30f;
    }
    fx4 mx = sc[0];
    #pragma unroll
    for (int ti = 1; ti < 5; ++ti)
      #pragma unroll
      for (int r = 0; r < 4; ++r) mx[r] = fmaxf(mx[r], sc[ti][r]);
    #pragma unroll
    for (int off = 1; off < 16; off <<= 1)
      #pragma unroll
      for (int r = 0; r < 4; ++r) mx[r] = fmaxf(mx[r], __shfl_xor(mx[r], off));
    fx4 sm = (fx4){0.f, 0.f, 0.f, 0.f};
    #pragma unroll
    for (int ti = 0; ti < 5; ++ti)
      #pragma unroll
      for (int r = 0; r < 4; ++r) {
        float e = __expf(sc[ti][r] - mx[r]);
        sc[ti][r] = e; sm[r] += e;
      }
    #pragma unroll
    for (int off = 1; off < 16; off <<= 1)
      #pragma unroll
      for (int r = 0; r < 4; ++r) sm[r] += __shfl_xor(sm[r], off);
    #pragma unroll
    for (int ti = 0; ti < 5; ++ti)
      #pragma unroll
      for (int r = 0; r < 4; ++r)
        Ps[qbase + qt * 16 + lg * 4 + r][ti * 16 + lr] = f2bf(sc[ti][r] / sm[r]);
  }

  // ---- PV (swapped: A=V[d][s], B=P[q][s] -> D[d][q]) ----
  #pragma unroll
  for (int qt = 0; qt < 2; ++qt) {
    int q = qbase + qt * 16 + lr;
    fx4 o[4];
    #pragma unroll
    for (int dt = 0; dt < 4; ++dt) o[dt] = (fx4){0.f, 0.f, 0.f, 0.f};
    #pragma unroll
    for (int ks = 0; ks < 3; ++ks) {
      bfx8 bb = *(const bfx8*)&Ps[q][ks * 32 + lg * 8];
      #pragma unroll
      for (int dt = 0; dt < 4; ++dt) {
        bfx8 a = *(const bfx8*)&Vs[dt * 16 + lr][ks * 32 + lg * 8];
        o[dt] = __builtin_amdgcn_mfma_f32_16x16x32_bf16(a, bb, o[dt], 0, 0, 0);
      }
    }
    #pragma unroll
    for (int dt = 0; dt < 4; ++dt) {
      int db = dt * 16 + lg * 4;
      int pb = ((db >> 3) ^ (q & 7));
      U2 pk;
      #pragma unroll
      for (int r = 0; r < 4; ++r) pk.h[r] = f2bf(o[dt][r]);
      *(uint2*)&QO[q * 64 + (pb << 3) + (db & 7)] = pk.v;
    }
  }
  __syncthreads();

  const size_t aobase = (size_t)b * 524288 + (size_t)n0 * 512 + head * 64;
  #pragma unroll
  for (int j = 0; j < 4; ++j) {
    int idx = j * 256 + t;
    int row = idx >> 3, cs = (idx & 7) * 8;
    *(uint4*)(aoT + aobase + (size_t)row * 512 + cs) = *(const uint4*)&QO[row * 64 + cs];
  }
}

extern "C" void kernel_launch(void* const* d_in, const int* in_sizes, int n_in,
                              void* d_out, int out_size, void* d_ws, size_t ws_size,
                              hipStream_t stream) {
  const float* x      = (const float*)d_in[0];
  const float* ctx    = (const float*)d_in[1];
  const float* gn_w   = (const float*)d_in[2];
  const float* gn_b   = (const float*)d_in[3];
  const float* q_w    = (const float*)d_in[4];
  const float* q_b    = (const float*)d_in[5];
  const float* kv_w   = (const float*)d_in[6];
  const float* kv_b   = (const float*)d_in[7];
  const float* proj_w = (const float*)d_in[8];
  const float* proj_b = (const float*)d_in[9];
  float* out = (float*)d_out;

  u16* p = (u16*)d_ws;
  u16* qw_bf  = p; p += 262144;          // 512*512
  u16* kvw_bf = p; p += 786432;          // 1024*768
  u16* pjw_bf = p; p += 262144;          // 512*512
  u16* ctx_bf = p; p += 16 * 128 * 768;  // padded rows
  u16* hT     = p; p += 8388608;         // 16*1024*512 (aliased as aoT later)
  u16* qT     = p; p += 8388608;
  u16* kvT_k  = p; p += 16 * 96 * 512;
  u16* kvV    = p; p += 16 * 512 * 80;
  u16* aoT    = hT;                      // alias: hT dead after Q-GEMM

  castw_kernel<<<256, 256, 0, stream>>>(q_w, qw_bf, 512, 65536);
  castw_kernel<<<768, 256, 0, stream>>>(kv_w, kvw_bf, 768, 196608);
  castw_kernel<<<256, 256, 0, stream>>>(proj_w, pjw_bf, 512, 65536);
  castctx_kernel<<<924, 256, 0, stream>>>(ctx, ctx_bf);

  gn_kernel<<<B_ * G_, 256, 0, stream>>>(x, gn_w, gn_b, hT);

  // KV: A=ctx [128pad][768], B=kv_w [1024][768] -> K^T + V
  gemm2_kernel<1><<<dim3(8, 1, B_), 256, 0, stream>>>(
      ctx_bf, kvw_bf, kv_b, nullptr, nullptr, kvT_k, kvV, 768, (size_t)128 * 768);

  // Q: A=hT [1024][512], B=q_w [512][512] -> qT
  gemm2_kernel<0><<<dim3(4, 8, B_), 256, 0, stream>>>(
      hT, qw_bf, q_b, nullptr, nullptr, qT, nullptr, 512, (size_t)1024 * 512);

  attn_kernel<<<dim3(8, HEADS_, B_), 256, 0, stream>>>(qT, kvT_k, kvV, aoT);

  // proj: A=aoT [1024][512], B=proj_w [512][512] -> f32 out + residual
  gemm2_kernel<2><<<dim3(4, 8, B_), 256, 0, stream>>>(
      aoT, pjw_bf, proj_b, x, out, nullptr, nullptr, 512, (size_t)1024 * 512);
}

// Round 5
// 117.393 us; speedup vs baseline: 4.3199x; 1.1833x over previous
//
#include <hip/hip_runtime.h>

#define B_   16
#define C_   512
#define HW_  1024
#define S_   77
#define CTX_ 768
#define HEADS_ 8
#define G_   8
#define EPS_ 1e-5f

typedef unsigned short u16;
typedef unsigned int u32;
typedef __attribute__((ext_vector_type(8))) short bfx8;   // 8 bf16 MFMA A/B frag
typedef __attribute__((ext_vector_type(4))) float fx4;    // MFMA C/D frag

union U2 { u16 h[4]; uint2 v; };

__device__ __forceinline__ u16 f2bf(float f) {
  union { float f; u32 u; } v; v.f = f;
  u32 u = v.u;
  return (u16)((u + 0x7FFFu + ((u >> 16) & 1u)) >> 16);
}

// async global->LDS, 16B per lane (lane-linear LDS dest, per-lane global src)
__device__ __forceinline__ void gload16(const u16* g, u16* l) {
  __builtin_amdgcn_global_load_lds((const __attribute__((address_space(1))) u32*)g,
                                   (__attribute__((address_space(3))) u32*)l, 16, 0, 0);
}

// ---------------- weight cast f32 -> bf16, row-swizzled ----------------
// out[m][k] stored: m*K + (k&~63) + (((k%64)/8 ^ (m&7))*8) + (k&7)
__global__ __launch_bounds__(256) void castw_kernel(const float* __restrict__ in,
                                                    u16* __restrict__ out, int K, int n4) {
  int i = blockIdx.x * 256 + threadIdx.x;
  if (i >= n4) return;
  float4 v = *(const float4*)(in + (size_t)i * 4);
  int K4 = K >> 2;
  int m = i / K4;
  int k = (i - m * K4) * 4;
  int pb = ((k & 63) >> 3) ^ (m & 7);
  size_t dst = (size_t)m * K + (k & ~63) + (pb << 3) + (k & 7);
  U2 pk;
  pk.h[0] = f2bf(v.x); pk.h[1] = f2bf(v.y); pk.h[2] = f2bf(v.z); pk.h[3] = f2bf(v.w);
  *(uint2*)(out + dst) = pk.v;
}

// ---------------- context cast: [b][77][768] f32 -> [b][128pad][768] bf16 swizzled ----------------
__global__ __launch_bounds__(256) void castctx_kernel(const float* __restrict__ in,
                                                      u16* __restrict__ out) {
  int i = blockIdx.x * 256 + threadIdx.x;
  if (i >= 16 * 77 * 192) return;
  int rg = i / 192;
  int k = (i - rg * 192) * 4;
  int b = rg / 77, s = rg - b * 77;
  float4 v = *(const float4*)(in + (size_t)i * 4);
  int pb = ((k & 63) >> 3) ^ (s & 7);
  size_t dst = ((size_t)b * 128 + s) * 768 + (k & ~63) + (pb << 3) + (k & 7);
  U2 pk;
  pk.h[0] = f2bf(v.x); pk.h[1] = f2bf(v.y); pk.h[2] = f2bf(v.z); pk.h[3] = f2bf(v.w);
  *(uint2*)(out + dst) = pk.v;
}

// ---------------- GroupNorm stage 1: per-(b,g,slice) partial sums ----------------
__global__ __launch_bounds__(256) void gn_stats(const float* __restrict__ x,
                                                float2* __restrict__ part) {
  int blk = blockIdx.x;                 // 1024: bg*8 + slice
  int bg = blk >> 3, slice = blk & 7;
  const float4* x4 = (const float4*)(x + (size_t)bg * 65536);
  int t = threadIdx.x;
  float s = 0.f, ss = 0.f;
  #pragma unroll
  for (int j = 0; j < 8; ++j) {
    float4 v = x4[slice * 2048 + j * 256 + t];
    s  += v.x + v.y + v.z + v.w;
    ss += v.x*v.x + v.y*v.y + v.z*v.z + v.w*v.w;
  }
  #pragma unroll
  for (int off = 32; off; off >>= 1) {
    s  += __shfl_down(s, off);
    ss += __shfl_down(ss, off);
  }
  __shared__ float rs[4], rss[4];
  int wid = t >> 6;
  if ((t & 63) == 0) { rs[wid] = s; rss[wid] = ss; }
  __syncthreads();
  if (t == 0)
    part[blk] = make_float2(rs[0] + rs[1] + rs[2] + rs[3],
                            rss[0] + rss[1] + rss[2] + rss[3]);
}

// ---------------- GroupNorm stage 2: fold partials -> (mean, rstd) per (b,g) ----------------
__global__ __launch_bounds__(128) void gn_stats2(const float2* __restrict__ part,
                                                 float2* __restrict__ stats) {
  int i = threadIdx.x;                  // 0..127
  float s = 0.f, ss = 0.f;
  #pragma unroll
  for (int j = 0; j < 8; ++j) { float2 pp = part[i * 8 + j]; s += pp.x; ss += pp.y; }
  const float invN = 1.0f / 65536.0f;
  float m = s * invN;
  float var = ss * invN - m * m;
  stats[i] = make_float2(m, rsqrtf(var + EPS_));
}

// ---------------- GroupNorm stage 3: normalize + transpose -> h^T swizzled ----------------
__global__ __launch_bounds__(256) void gn_apply(const float* __restrict__ x,
                                                const float* __restrict__ w,
                                                const float* __restrict__ bgn,
                                                const float2* __restrict__ stats,
                                                u16* __restrict__ hT) {
  int blk = blockIdx.x;                 // 1024: bg*8 + nt
  int nt = blk & 7, bg = blk >> 3;
  int batch = bg >> 3, g = bg & 7;
  const float4* x4 = (const float4*)(x + ((size_t)batch * C_ + (size_t)g * 64) * HW_);
  float2 st = stats[bg];
  int t = threadIdx.x;
  int c = t >> 2;                       // 0..63
  int cg = g * 64 + c;
  float wc_ = w[cg] * st.y;
  float bc_ = bgn[cg] - st.x * wc_;
  __shared__ u16 T2[128 * 72];
  #pragma unroll
  for (int j4 = 0; j4 < 8; ++j4) {
    int f4 = (t & 3) + j4 * 4;          // 0..31
    float4 v = x4[c * 256 + nt * 32 + f4];
    const float* vp = &v.x;
    int nl = f4 * 4;
    #pragma unroll
    for (int e = 0; e < 4; ++e) {
      int n = nl + e;
      int pb = ((c >> 3) ^ (n & 7));
      T2[n * 72 + (pb << 3) + (c & 7)] = f2bf(vp[e] * wc_ + bc_);
    }
  }
  __syncthreads();
  #pragma unroll
  for (int j = 0; j < 4; ++j) {
    int idx = j * 256 + t;
    int row = idx >> 3, cs = (idx & 7) * 8;
    uint4 vv = *(const uint4*)&T2[row * 72 + cs];
    *(uint4*)(hT + ((size_t)batch * 1024 + nt * 128 + row) * 512 + g * 64 + cs) = vv;
  }
}

// ---------------- m97-style GEMM: D[m][n] = A[b][m][:] . Bw[n][:] + bias[n] ----------------
// A: per-batch activations [Mrows][K] swizzled; Bw: weights [N][K] swizzled.
// EPI 0: q^T bf16 out (rows m, cols n, swizzled). EPI 1: kv split epilogue. EPI 2: f32 out + residual.
template<int EPI>
__global__ __launch_bounds__(256) void gemm2_kernel(
    const u16* __restrict__ A, const u16* __restrict__ Bw,
    const float* __restrict__ bias, const float* __restrict__ resid,
    float* __restrict__ outf, u16* __restrict__ o16a, u16* __restrict__ o16b,
    int K, size_t strideA)
{
  __shared__ u16 As[128 * 64];
  __shared__ u16 Bs[128 * 64];
  int t = threadIdx.x;
  int b = blockIdx.z;
  int n0 = blockIdx.x * 128, m0 = blockIdx.y * 128;
  const u16* aBase = A + (size_t)b * strideA + (size_t)(m0 + (t >> 3)) * K + (t & 7) * 8;
  const u16* bBase = Bw + (size_t)(n0 + (t >> 3)) * K + (t & 7) * 8;
  int wid = t >> 6, l = t & 63;
  int wr = wid >> 1, wc = wid & 1;
  int lr = l & 15, lg = l >> 4;
  fx4 acc[4][4];
  #pragma unroll
  for (int i = 0; i < 4; ++i)
    #pragma unroll
    for (int j = 0; j < 4; ++j) acc[i][j] = (fx4){0.f, 0.f, 0.f, 0.f};

  for (int k0 = 0; k0 < K; k0 += 64) {
    __syncthreads();
    #pragma unroll
    for (int i = 0; i < 4; ++i) {
      gload16(aBase + k0 + (size_t)i * 32 * K, As + i * 2048 + t * 8);
      gload16(bBase + k0 + (size_t)i * 32 * K, Bs + i * 2048 + t * 8);
    }
    __syncthreads();
    #pragma unroll
    for (int kk = 0; kk < 2; ++kk) {
      bfx8 af[4], bf[4];
      int xr = (lr & 7);
      #pragma unroll
      for (int i = 0; i < 4; ++i) {
        int lb = kk * 4 + lg;
        af[i] = *(const bfx8*)&As[(wr * 64 + i * 16 + lr) * 64 + ((lb ^ xr) << 3)];
        bf[i] = *(const bfx8*)&Bs[(wc * 64 + i * 16 + lr) * 64 + ((lb ^ xr) << 3)];
      }
      #pragma unroll
      for (int mi = 0; mi < 4; ++mi)
        #pragma unroll
        for (int ni = 0; ni < 4; ++ni)
          acc[mi][ni] = __builtin_amdgcn_mfma_f32_16x16x32_bf16(af[mi], bf[ni], acc[mi][ni], 0, 0, 0);
    }
  }

  if (EPI == 0) {
    // stage per-wave [64 m][64 c] swizzled tile in LDS, then linear copy to q^T
    __syncthreads();
    u16* T = ((wid & 2) ? Bs : As) + (wid & 1) * 4096;
    #pragma unroll
    for (int mi = 0; mi < 4; ++mi)
      #pragma unroll
      for (int ni = 0; ni < 4; ++ni) {
        int cl = ni * 16 + lr;
        float bb = bias[n0 + wc * 64 + cl];
        #pragma unroll
        for (int r = 0; r < 4; ++r) {
          int ml = mi * 16 + lg * 4 + r;
          int pb = ((cl >> 3) ^ (ml & 7));
          T[ml * 64 + (pb << 3) + (cl & 7)] = f2bf(acc[mi][ni][r] + bb);
        }
      }
    #pragma unroll
    for (int j = 0; j < 8; ++j) {
      int idx = j * 64 + l;
      int row = idx >> 3, cs = (idx & 7) * 8;
      uint4 v = *(const uint4*)&T[row * 64 + cs];
      *(uint4*)(o16a + (size_t)b * 524288 + (size_t)(m0 + wr * 64 + row) * 512
                + n0 + wc * 64 + cs) = v;
    }
  } else if (EPI == 2) {
    float* O = outf + (size_t)b * 524288;
    const float* R = resid + (size_t)b * 524288;
    #pragma unroll
    for (int ni = 0; ni < 4; ++ni) {
      int cc = n0 + wc * 64 + ni * 16 + lr;
      float bb = bias[cc];
      #pragma unroll
      for (int mi = 0; mi < 4; ++mi) {
        size_t off = (size_t)cc * 1024 + m0 + wr * 64 + mi * 16 + lg * 4;
        float4 rv = *(const float4*)(R + off);
        float4 ov;
        ov.x = acc[mi][ni][0] + bb + rv.x;
        ov.y = acc[mi][ni][1] + bb + rv.y;
        ov.z = acc[mi][ni][2] + bb + rv.z;
        ov.w = acc[mi][ni][3] + bb + rv.w;
        *(float4*)(O + off) = ov;
      }
    }
  } else {
    // EPI 1: n<512 -> K^T[s][o] swizzled scatter; n>=512 -> V[d][s] uint2
    #pragma unroll
    for (int ni = 0; ni < 4; ++ni) {
      int o = n0 + wc * 64 + ni * 16 + lr;
      float bb = bias[o];
      #pragma unroll
      for (int mi = 0; mi < 4; ++mi) {
        int sb = wr * 64 + mi * 16 + lg * 4;   // m0 == 0
        if (o < 512) {
          #pragma unroll
          for (int r = 0; r < 4; ++r) {
            int sidx = sb + r;
            if (sidx < 96) {
              int ob = (o & ~63) | (((((o >> 3) & 7) ^ (sidx & 7))) << 3) | (o & 7);
              o16a[(size_t)b * 49152 + (size_t)sidx * 512 + ob] = f2bf(acc[mi][ni][r] + bb);
            }
          }
        } else if (sb < 80) {
          U2 pk;
          #pragma unroll
          for (int r = 0; r < 4; ++r) pk.h[r] = f2bf(acc[mi][ni][r] + bb);
          *(uint2*)(o16b + (size_t)b * 40960 + (size_t)(o - 512) * 80 + sb) = pk.v;
        }
      }
    }
  }
}

// ---------------- MFMA attention: block = (b, head, 128-query chunk) ----------------
// qT: [b][n][512] swizzled; kvK: [b][96][512] swizzled (K^T); kvV: [b][512][80] ([d][s])
// aoT out: [b][n][512] swizzled
__global__ __launch_bounds__(256) void attn_kernel(const u16* __restrict__ qT,
                                                   const u16* __restrict__ kvK,
                                                   const u16* __restrict__ kvV,
                                                   u16* __restrict__ aoT) {
  __shared__ u16 QO[128 * 64];      // Q swizzled; later O^T [q][64 d] swizzled
  __shared__ u16 Ks[96 * 64];       // swizzled [s][d]
  __shared__ u16 Vs[64][104];       // [d][s], s<96 valid (zeros 80..95)
  __shared__ u16 Ps[128][104];      // [q][s] bf16
  int t = threadIdx.x;
  int n0 = blockIdx.x * 128, head = blockIdx.y, b = blockIdx.z;

  const u16* qsrc = qT + (size_t)b * 524288 + (size_t)(n0 + (t >> 3)) * 512 + head * 64 + (t & 7) * 8;
  #pragma unroll
  for (int i = 0; i < 4; ++i) gload16(qsrc + (size_t)i * 32 * 512, QO + i * 2048 + t * 8);
  const u16* ksrc = kvK + (size_t)b * 49152 + (size_t)(t >> 3) * 512 + head * 64 + (t & 7) * 8;
  #pragma unroll
  for (int i = 0; i < 3; ++i) gload16(ksrc + (size_t)i * 32 * 512, Ks + i * 2048 + t * 8);
  const u16* vsrc = kvV + (size_t)b * 40960 + (size_t)head * 64 * 80;
  for (int i = t; i < 640; i += 256) {
    int d = i / 10, sb = i - d * 10;
    *(uint4*)&Vs[d][sb * 8] = *(const uint4*)(vsrc + d * 80 + sb * 8);
  }
  { // zero Vs s in [80,96) and Ps s in [80,96)
    if (t < 128) {
      int d = t >> 1, part = t & 1;
      *(uint4*)&Vs[d][80 + part * 8] = (uint4){0u, 0u, 0u, 0u};
    }
    int row = t >> 1, part = t & 1;
    *(uint4*)&Ps[row][80 + part * 8] = (uint4){0u, 0u, 0u, 0u};
  }
  __syncthreads();

  int wid = t >> 6, l = t & 63;
  int lr = l & 15, lg = l >> 4, xr = lr & 7;
  int qbase = wid * 32;

  // ---- QK^T + softmax + P ----
  #pragma unroll
  for (int qt = 0; qt < 2; ++qt) {
    int qrow = qbase + qt * 16 + lr;
    fx4 sc[5];
    #pragma unroll
    for (int ti = 0; ti < 5; ++ti) sc[ti] = (fx4){0.f, 0.f, 0.f, 0.f};
    #pragma unroll
    for (int ks = 0; ks < 2; ++ks) {
      int lb = ks * 4 + lg;
      bfx8 a = *(const bfx8*)&QO[qrow * 64 + ((lb ^ xr) << 3)];
      #pragma unroll
      for (int ti = 0; ti < 5; ++ti) {
        bfx8 bb = *(const bfx8*)&Ks[(ti * 16 + lr) * 64 + ((lb ^ xr) << 3)];
        sc[ti] = __builtin_amdgcn_mfma_f32_16x16x32_bf16(a, bb, sc[ti], 0, 0, 0);
      }
    }
    #pragma unroll
    for (int ti = 0; ti < 5; ++ti) {
      bool valid = (ti * 16 + lr) < S_;
      #pragma unroll
      for (int r = 0; r < 4; ++r)
        sc[ti][r] = valid ? sc[ti][r] * 0.125f : -1e30f;
    }
    fx4 mx = sc[0];
    #pragma unroll
    for (int ti = 1; ti < 5; ++ti)
      #pragma unroll
      for (int r = 0; r < 4; ++r) mx[r] = fmaxf(mx[r], sc[ti][r]);
    #pragma unroll
    for (int off = 1; off < 16; off <<= 1)
      #pragma unroll
      for (int r = 0; r < 4; ++r) mx[r] = fmaxf(mx[r], __shfl_xor(mx[r], off));
    fx4 sm = (fx4){0.f, 0.f, 0.f, 0.f};
    #pragma unroll
    for (int ti = 0; ti < 5; ++ti)
      #pragma unroll
      for (int r = 0; r < 4; ++r) {
        float e = __expf(sc[ti][r] - mx[r]);
        sc[ti][r] = e; sm[r] += e;
      }
    #pragma unroll
    for (int off = 1; off < 16; off <<= 1)
      #pragma unroll
      for (int r = 0; r < 4; ++r) sm[r] += __shfl_xor(sm[r], off);
    #pragma unroll
    for (int ti = 0; ti < 5; ++ti)
      #pragma unroll
      for (int r = 0; r < 4; ++r)
        Ps[qbase + qt * 16 + lg * 4 + r][ti * 16 + lr] = f2bf(sc[ti][r] / sm[r]);
  }

  // ---- PV (swapped: A=V[d][s], B=P[q][s] -> D[d][q]) ----
  #pragma unroll
  for (int qt = 0; qt < 2; ++qt) {
    int q = qbase + qt * 16 + lr;
    fx4 o[4];
    #pragma unroll
    for (int dt = 0; dt < 4; ++dt) o[dt] = (fx4){0.f, 0.f, 0.f, 0.f};
    #pragma unroll
    for (int ks = 0; ks < 3; ++ks) {
      bfx8 bb = *(const bfx8*)&Ps[q][ks * 32 + lg * 8];
      #pragma unroll
      for (int dt = 0; dt < 4; ++dt) {
        bfx8 a = *(const bfx8*)&Vs[dt * 16 + lr][ks * 32 + lg * 8];
        o[dt] = __builtin_amdgcn_mfma_f32_16x16x32_bf16(a, bb, o[dt], 0, 0, 0);
      }
    }
    #pragma unroll
    for (int dt = 0; dt < 4; ++dt) {
      int db = dt * 16 + lg * 4;
      int pb = ((db >> 3) ^ (q & 7));
      U2 pk;
      #pragma unroll
      for (int r = 0; r < 4; ++r) pk.h[r] = f2bf(o[dt][r]);
      *(uint2*)&QO[q * 64 + (pb << 3) + (db & 7)] = pk.v;
    }
  }
  __syncthreads();

  const size_t aobase = (size_t)b * 524288 + (size_t)n0 * 512 + head * 64;
  #pragma unroll
  for (int j = 0; j < 4; ++j) {
    int idx = j * 256 + t;
    int row = idx >> 3, cs = (idx & 7) * 8;
    *(uint4*)(aoT + aobase + (size_t)row * 512 + cs) = *(const uint4*)&QO[row * 64 + cs];
  }
}

extern "C" void kernel_launch(void* const* d_in, const int* in_sizes, int n_in,
                              void* d_out, int out_size, void* d_ws, size_t ws_size,
                              hipStream_t stream) {
  const float* x      = (const float*)d_in[0];
  const float* ctx    = (const float*)d_in[1];
  const float* gn_w   = (const float*)d_in[2];
  const float* gn_b   = (const float*)d_in[3];
  const float* q_w    = (const float*)d_in[4];
  const float* q_b    = (const float*)d_in[5];
  const float* kv_w   = (const float*)d_in[6];
  const float* kv_b   = (const float*)d_in[7];
  const float* proj_w = (const float*)d_in[8];
  const float* proj_b = (const float*)d_in[9];
  float* out = (float*)d_out;

  u16* p = (u16*)d_ws;
  u16* qw_bf  = p; p += 262144;          // 512*512
  u16* kvw_bf = p; p += 786432;          // 1024*768
  u16* pjw_bf = p; p += 262144;          // 512*512
  u16* ctx_bf = p; p += 16 * 128 * 768;  // padded rows
  u16* hT     = p; p += 8388608;         // 16*1024*512 (aliased as aoT later)
  u16* qT     = p; p += 8388608;
  u16* kvT_k  = p; p += 16 * 96 * 512;
  u16* kvV    = p; p += 16 * 512 * 80;
  float2* gpart  = (float2*)p; p += 1024 * 4;   // 1024 float2
  float2* gstats = (float2*)p; p += 128 * 4;    // 128 float2
  u16* aoT    = hT;                      // alias: hT dead after Q-GEMM

  castw_kernel<<<256, 256, 0, stream>>>(q_w, qw_bf, 512, 65536);
  castw_kernel<<<768, 256, 0, stream>>>(kv_w, kvw_bf, 768, 196608);
  castw_kernel<<<256, 256, 0, stream>>>(proj_w, pjw_bf, 512, 65536);
  castctx_kernel<<<924, 256, 0, stream>>>(ctx, ctx_bf);

  gn_stats<<<1024, 256, 0, stream>>>(x, gpart);
  gn_stats2<<<1, 128, 0, stream>>>(gpart, gstats);
  gn_apply<<<1024, 256, 0, stream>>>(x, gn_w, gn_b, gstats, hT);

  // KV: A=ctx [128pad][768], B=kv_w [1024][768] -> K^T + V
  gemm2_kernel<1><<<dim3(8, 1, B_), 256, 0, stream>>>(
      ctx_bf, kvw_bf, kv_b, nullptr, nullptr, kvT_k, kvV, 768, (size_t)128 * 768);

  // Q: A=hT [1024][512], B=q_w [512][512] -> qT
  gemm2_kernel<0><<<dim3(4, 8, B_), 256, 0, stream>>>(
      hT, qw_bf, q_b, nullptr, nullptr, qT, nullptr, 512, (size_t)1024 * 512);

  attn_kernel<<<dim3(8, HEADS_, B_), 256, 0, stream>>>(qT, kvT_k, kvV, aoT);

  // proj: A=aoT [1024][512], B=proj_w [512][512] -> f32 out + residual
  gemm2_kernel<2><<<dim3(4, 8, B_), 256, 0, stream>>>(
      aoT, pjw_bf, proj_b, x, out, nullptr, nullptr, 512, (size_t)1024 * 512);
}

// Round 6
// 111.501 us; speedup vs baseline: 4.5482x; 1.0528x over previous
//
#include <hip/hip_runtime.h>

#define B_   16
#define C_   512
#define HW_  1024
#define S_   77
#define CTX_ 768
#define HEADS_ 8
#define G_   8
#define EPS_ 1e-5f

typedef unsigned short u16;
typedef unsigned int u32;
typedef __attribute__((ext_vector_type(8))) short bfx8;   // 8 bf16 MFMA A/B frag
typedef __attribute__((ext_vector_type(4))) float fx4;    // MFMA C/D frag

union U2 { u16 h[4]; uint2 v; };

__device__ __forceinline__ u16 f2bf(float f) {
  union { float f; u32 u; } v; v.f = f;
  u32 u = v.u;
  return (u16)((u + 0x7FFFu + ((u >> 16) & 1u)) >> 16);
}

// async global->LDS, 16B per lane (lane-linear LDS dest, per-lane global src)
__device__ __forceinline__ void gload16(const u16* g, u16* l) {
  __builtin_amdgcn_global_load_lds((const __attribute__((address_space(1))) u32*)g,
                                   (__attribute__((address_space(3))) u32*)l, 16, 0, 0);
}

// ---------------- weight cast f32 -> bf16, row-swizzled ----------------
// out[m][k] stored: m*K + (k&~63) + (((k%64)/8 ^ (m&7))*8) + (k&7)
__global__ __launch_bounds__(256) void castw_kernel(const float* __restrict__ in,
                                                    u16* __restrict__ out, int K, int n4) {
  int i = blockIdx.x * 256 + threadIdx.x;
  if (i >= n4) return;
  float4 v = *(const float4*)(in + (size_t)i * 4);
  int K4 = K >> 2;
  int m = i / K4;
  int k = (i - m * K4) * 4;
  int pb = ((k & 63) >> 3) ^ (m & 7);
  size_t dst = (size_t)m * K + (k & ~63) + (pb << 3) + (k & 7);
  U2 pk;
  pk.h[0] = f2bf(v.x); pk.h[1] = f2bf(v.y); pk.h[2] = f2bf(v.z); pk.h[3] = f2bf(v.w);
  *(uint2*)(out + dst) = pk.v;
}

// ---------------- context cast: [b][77][768] f32 -> [b][128pad][768] bf16 swizzled ----------------
__global__ __launch_bounds__(256) void castctx_kernel(const float* __restrict__ in,
                                                      u16* __restrict__ out) {
  int i = blockIdx.x * 256 + threadIdx.x;
  if (i >= 16 * 77 * 192) return;
  int rg = i / 192;
  int k = (i - rg * 192) * 4;
  int b = rg / 77, s = rg - b * 77;
  float4 v = *(const float4*)(in + (size_t)i * 4);
  int pb = ((k & 63) >> 3) ^ (s & 7);
  size_t dst = ((size_t)b * 128 + s) * 768 + (k & ~63) + (pb << 3) + (k & 7);
  U2 pk;
  pk.h[0] = f2bf(v.x); pk.h[1] = f2bf(v.y); pk.h[2] = f2bf(v.z); pk.h[3] = f2bf(v.w);
  *(uint2*)(out + dst) = pk.v;
}

// ---------------- GroupNorm stage 1: per-(b,g,slice) partial sums ----------------
__global__ __launch_bounds__(256) void gn_stats(const float* __restrict__ x,
                                                float2* __restrict__ part) {
  int blk = blockIdx.x;                 // 1024: bg*8 + slice
  int bg = blk >> 3, slice = blk & 7;
  const float4* x4 = (const float4*)(x + (size_t)bg * 65536);
  int t = threadIdx.x;
  float s = 0.f, ss = 0.f;
  #pragma unroll
  for (int j = 0; j < 8; ++j) {
    float4 v = x4[slice * 2048 + j * 256 + t];
    s  += v.x + v.y + v.z + v.w;
    ss += v.x*v.x + v.y*v.y + v.z*v.z + v.w*v.w;
  }
  #pragma unroll
  for (int off = 32; off; off >>= 1) {
    s  += __shfl_down(s, off);
    ss += __shfl_down(ss, off);
  }
  __shared__ float rs[4], rss[4];
  int wid = t >> 6;
  if ((t & 63) == 0) { rs[wid] = s; rss[wid] = ss; }
  __syncthreads();
  if (t == 0)
    part[blk] = make_float2(rs[0] + rs[1] + rs[2] + rs[3],
                            rss[0] + rss[1] + rss[2] + rss[3]);
}

// ---------------- GroupNorm stage 2: fold partials -> (mean, rstd) per (b,g) ----------------
__global__ __launch_bounds__(128) void gn_stats2(const float2* __restrict__ part,
                                                 float2* __restrict__ stats) {
  int i = threadIdx.x;                  // 0..127
  float s = 0.f, ss = 0.f;
  #pragma unroll
  for (int j = 0; j < 8; ++j) { float2 pp = part[i * 8 + j]; s += pp.x; ss += pp.y; }
  const float invN = 1.0f / 65536.0f;
  float m = s * invN;
  float var = ss * invN - m * m;
  stats[i] = make_float2(m, rsqrtf(var + EPS_));
}

// ---------------- GroupNorm stage 3: normalize + transpose (4x4 reg blocks) -> h^T swizzled ----------------
__global__ __launch_bounds__(256) void gn_apply(const float* __restrict__ x,
                                                const float* __restrict__ w,
                                                const float* __restrict__ bgn,
                                                const float2* __restrict__ stats,
                                                u16* __restrict__ hT) {
  int blk = blockIdx.x;                 // 1024: bg*8 + nt
  int nt = blk & 7, bg = blk >> 3;
  int batch = bg >> 3, g = bg & 7;
  const float4* x4 = (const float4*)(x + ((size_t)batch * C_ + (size_t)g * 64) * HW_);
  float2 st = stats[bg];
  int t = threadIdx.x;
  __shared__ u16 T2[128 * 72];
  int n4i = t & 31;                     // n-group (4 n each), 32 groups
  int c4b = t >> 5;                     // 0..7
  #pragma unroll
  for (int j = 0; j < 2; ++j) {
    int c4 = c4b + j * 8;               // 0..15, channels c4*4..c4*4+3
    float4 v[4];
    float wcs[4], bcs[4];
    #pragma unroll
    for (int e = 0; e < 4; ++e) {
      int c = c4 * 4 + e;
      v[e] = x4[(size_t)c * 256 + nt * 32 + n4i];
      int cg = g * 64 + c;
      float wc_ = w[cg] * st.y;
      wcs[e] = wc_;
      bcs[e] = bgn[cg] - st.x * wc_;
    }
    int cbase = c4 * 4;
    #pragma unroll
    for (int ne = 0; ne < 4; ++ne) {
      int n = n4i * 4 + ne;
      int pb = (cbase >> 3) ^ (n & 7);
      U2 pk;
      pk.h[0] = f2bf(((const float*)&v[0])[ne] * wcs[0] + bcs[0]);
      pk.h[1] = f2bf(((const float*)&v[1])[ne] * wcs[1] + bcs[1]);
      pk.h[2] = f2bf(((const float*)&v[2])[ne] * wcs[2] + bcs[2]);
      pk.h[3] = f2bf(((const float*)&v[3])[ne] * wcs[3] + bcs[3]);
      *(uint2*)&T2[n * 72 + (pb << 3) + (cbase & 7)] = pk.v;
    }
  }
  __syncthreads();
  #pragma unroll
  for (int j = 0; j < 4; ++j) {
    int idx = j * 256 + t;
    int row = idx >> 3, cs = (idx & 7) * 8;
    uint4 vv = *(const uint4*)&T2[row * 72 + cs];
    *(uint4*)(hT + ((size_t)batch * 1024 + nt * 128 + row) * 512 + g * 64 + cs) = vv;
  }
}

// ---------------- m97-style GEMM: D[m][n] = A[b][m][:] . Bw[n][:] + bias[n] ----------------
// EPI 1: kv split epilogue. EPI 2: f32 out + residual.
template<int EPI>
__global__ __launch_bounds__(256) void gemm2_kernel(
    const u16* __restrict__ A, const u16* __restrict__ Bw,
    const float* __restrict__ bias, const float* __restrict__ resid,
    float* __restrict__ outf, u16* __restrict__ o16a, u16* __restrict__ o16b,
    int K, size_t strideA)
{
  __shared__ u16 As[128 * 64];
  __shared__ u16 Bs[128 * 64];
  int t = threadIdx.x;
  int b = blockIdx.z;
  int n0 = blockIdx.x * 128, m0 = blockIdx.y * 128;
  const u16* aBase = A + (size_t)b * strideA + (size_t)(m0 + (t >> 3)) * K + (t & 7) * 8;
  const u16* bBase = Bw + (size_t)(n0 + (t >> 3)) * K + (t & 7) * 8;
  int wid = t >> 6, l = t & 63;
  int wr = wid >> 1, wc = wid & 1;
  int lr = l & 15, lg = l >> 4;
  fx4 acc[4][4];
  #pragma unroll
  for (int i = 0; i < 4; ++i)
    #pragma unroll
    for (int j = 0; j < 4; ++j) acc[i][j] = (fx4){0.f, 0.f, 0.f, 0.f};

  for (int k0 = 0; k0 < K; k0 += 64) {
    __syncthreads();
    #pragma unroll
    for (int i = 0; i < 4; ++i) {
      gload16(aBase + k0 + (size_t)i * 32 * K, As + i * 2048 + t * 8);
      gload16(bBase + k0 + (size_t)i * 32 * K, Bs + i * 2048 + t * 8);
    }
    __syncthreads();
    #pragma unroll
    for (int kk = 0; kk < 2; ++kk) {
      bfx8 af[4], bf[4];
      int xr = (lr & 7);
      #pragma unroll
      for (int i = 0; i < 4; ++i) {
        int lb = kk * 4 + lg;
        af[i] = *(const bfx8*)&As[(wr * 64 + i * 16 + lr) * 64 + ((lb ^ xr) << 3)];
        bf[i] = *(const bfx8*)&Bs[(wc * 64 + i * 16 + lr) * 64 + ((lb ^ xr) << 3)];
      }
      #pragma unroll
      for (int mi = 0; mi < 4; ++mi)
        #pragma unroll
        for (int ni = 0; ni < 4; ++ni)
          acc[mi][ni] = __builtin_amdgcn_mfma_f32_16x16x32_bf16(af[mi], bf[ni], acc[mi][ni], 0, 0, 0);
    }
  }

  if (EPI == 2) {
    float* O = outf + (size_t)b * 524288;
    const float* R = resid + (size_t)b * 524288;
    #pragma unroll
    for (int ni = 0; ni < 4; ++ni) {
      int cc = n0 + wc * 64 + ni * 16 + lr;
      float bb = bias[cc];
      #pragma unroll
      for (int mi = 0; mi < 4; ++mi) {
        size_t off = (size_t)cc * 1024 + m0 + wr * 64 + mi * 16 + lg * 4;
        float4 rv = *(const float4*)(R + off);
        float4 ov;
        ov.x = acc[mi][ni][0] + bb + rv.x;
        ov.y = acc[mi][ni][1] + bb + rv.y;
        ov.z = acc[mi][ni][2] + bb + rv.z;
        ov.w = acc[mi][ni][3] + bb + rv.w;
        *(float4*)(O + off) = ov;
      }
    }
  } else {
    // EPI 1: n<512 -> K^T[s][o] swizzled scatter; n>=512 -> V[d][s] uint2
    #pragma unroll
    for (int ni = 0; ni < 4; ++ni) {
      int o = n0 + wc * 64 + ni * 16 + lr;
      float bb = bias[o];
      #pragma unroll
      for (int mi = 0; mi < 4; ++mi) {
        int sb = wr * 64 + mi * 16 + lg * 4;   // m0 == 0
        if (o < 512) {
          #pragma unroll
          for (int r = 0; r < 4; ++r) {
            int sidx = sb + r;
            if (sidx < 96) {
              int ob = (o & ~63) | (((((o >> 3) & 7) ^ (sidx & 7))) << 3) | (o & 7);
              o16a[(size_t)b * 49152 + (size_t)sidx * 512 + ob] = f2bf(acc[mi][ni][r] + bb);
            }
          }
        } else if (sb < 80) {
          U2 pk;
          #pragma unroll
          for (int r = 0; r < 4; ++r) pk.h[r] = f2bf(acc[mi][ni][r] + bb);
          *(uint2*)(o16b + (size_t)b * 40960 + (size_t)(o - 512) * 80 + sb) = pk.v;
        }
      }
    }
  }
}

// ---------------- fused Q-GEMM + MFMA attention: block = (b, head, 128-query chunk) ----------------
// hT: [b][n][512] swizzled; qw: [512][512] swizzled; kvK: [b][96][512] swizzled; kvV: [b][512][80]
// aoT out: [b][n][512] swizzled
__global__ __launch_bounds__(256) void qattn_kernel(const u16* __restrict__ hT,
                                                    const u16* __restrict__ qw,
                                                    const float* __restrict__ q_b,
                                                    const u16* __restrict__ kvK,
                                                    const u16* __restrict__ kvV,
                                                    u16* __restrict__ aoT) {
  __shared__ u16 SH[34304];
  u16* QO = SH;                 // 8192: q swizzled [q][64 d]; later O
  u16* Ks = SH + 8192;          // 6144: swizzled [s][d]
  u16* Vs = SH + 14336;         // 64*104: [d][s]
  u16* UN = SH + 20992;         // 13312: As(8192)+Bs(4096) staging, then Ps[128][104]
  u16* As = UN;
  u16* Bs = UN + 8192;
  u16* Ps = UN;

  int t = threadIdx.x;
  int n0 = blockIdx.x * 128, head = blockIdx.y, b = blockIdx.z;

  // ---- issue K gload + V copy (independent LDS regions) ----
  const u16* ksrc = kvK + (size_t)b * 49152 + (size_t)(t >> 3) * 512 + head * 64 + (t & 7) * 8;
  #pragma unroll
  for (int i = 0; i < 3; ++i) gload16(ksrc + (size_t)i * 32 * 512, Ks + i * 2048 + t * 8);
  const u16* vsrc = kvV + (size_t)b * 40960 + (size_t)head * 64 * 80;
  for (int i = t; i < 640; i += 256) {
    int d = i / 10, sb = i - d * 10;
    *(uint4*)&Vs[d * 104 + sb * 8] = *(const uint4*)(vsrc + d * 80 + sb * 8);
  }
  if (t < 128) {
    int d = t >> 1, part = t & 1;
    *(uint4*)&Vs[d * 104 + 80 + part * 8] = (uint4){0u, 0u, 0u, 0u};
  }

  int wid = t >> 6, l = t & 63;
  int lr = l & 15, lg = l >> 4, xr = lr & 7;
  int qbase = wid * 32;

  // ---- q-GEMM: QO[128 q][64 d] = hT[n0+q][:] . qw[head*64+d][:] + q_b ----
  {
    const u16* aBase = hT + (size_t)b * 524288 + (size_t)(n0 + (t >> 3)) * 512 + (t & 7) * 8;
    const u16* bBase = qw + (size_t)(head * 64 + (t >> 3)) * 512 + (t & 7) * 8;
    fx4 acc[2][4];
    #pragma unroll
    for (int i = 0; i < 2; ++i)
      #pragma unroll
      for (int j = 0; j < 4; ++j) acc[i][j] = (fx4){0.f, 0.f, 0.f, 0.f};
    for (int k0 = 0; k0 < 512; k0 += 64) {
      __syncthreads();
      #pragma unroll
      for (int i = 0; i < 4; ++i) gload16(aBase + k0 + (size_t)i * 32 * 512, As + i * 2048 + t * 8);
      #pragma unroll
      for (int i = 0; i < 2; ++i) gload16(bBase + k0 + (size_t)i * 32 * 512, Bs + i * 2048 + t * 8);
      __syncthreads();
      #pragma unroll
      for (int kk = 0; kk < 2; ++kk) {
        int lb = kk * 4 + lg;
        bfx8 af[2], bf[4];
        #pragma unroll
        for (int i = 0; i < 2; ++i)
          af[i] = *(const bfx8*)&As[(qbase + i * 16 + lr) * 64 + ((lb ^ xr) << 3)];
        #pragma unroll
        for (int i = 0; i < 4; ++i)
          bf[i] = *(const bfx8*)&Bs[(i * 16 + lr) * 64 + ((lb ^ xr) << 3)];
        #pragma unroll
        for (int mi = 0; mi < 2; ++mi)
          #pragma unroll
          for (int ni = 0; ni < 4; ++ni)
            acc[mi][ni] = __builtin_amdgcn_mfma_f32_16x16x32_bf16(af[mi], bf[ni], acc[mi][ni], 0, 0, 0);
      }
    }
    // scatter D+bias into QO (swizzled [q][d])
    #pragma unroll
    for (int ni = 0; ni < 4; ++ni) {
      int d = ni * 16 + lr;
      float bb = q_b[head * 64 + d];
      #pragma unroll
      for (int mi = 0; mi < 2; ++mi) {
        #pragma unroll
        for (int r = 0; r < 4; ++r) {
          int q = qbase + mi * 16 + lg * 4 + r;
          QO[q * 64 + ((((d >> 3) ^ (q & 7))) << 3) + (d & 7)] = f2bf(acc[mi][ni][r] + bb);
        }
      }
    }
  }
  __syncthreads();   // QO complete; As/Bs dead -> Ps region usable

  // ---- zero Ps pad cols [80,96) (wave-local rows: t>>1 in own wave range) ----
  {
    int row = t >> 1, part = t & 1;
    *(uint4*)&Ps[row * 104 + 80 + part * 8] = (uint4){0u, 0u, 0u, 0u};
  }

  // ---- QK^T + softmax + P ----
  #pragma unroll
  for (int qt = 0; qt < 2; ++qt) {
    int qrow = qbase + qt * 16 + lr;
    fx4 sc[5];
    #pragma unroll
    for (int ti = 0; ti < 5; ++ti) sc[ti] = (fx4){0.f, 0.f, 0.f, 0.f};
    #pragma unroll
    for (int ks = 0; ks < 2; ++ks) {
      int lb = ks * 4 + lg;
      bfx8 a = *(const bfx8*)&QO[qrow * 64 + ((lb ^ xr) << 3)];
      #pragma unroll
      for (int ti = 0; ti < 5; ++ti) {
        bfx8 bb = *(const bfx8*)&Ks[(ti * 16 + lr) * 64 + ((lb ^ xr) << 3)];
        sc[ti] = __builtin_amdgcn_mfma_f32_16x16x32_bf16(a, bb, sc[ti], 0, 0, 0);
      }
    }
    #pragma unroll
    for (int ti = 0; ti < 5; ++ti) {
      bool valid = (ti * 16 + lr) < S_;
      #pragma unroll
      for (int r = 0; r < 4; ++r)
        sc[ti][r] = valid ? sc[ti][r] * 0.125f : -1e30f;
    }
    fx4 mx = sc[0];
    #pragma unroll
    for (int ti = 1; ti < 5; ++ti)
      #pragma unroll
      for (int r = 0; r < 4; ++r) mx[r] = fmaxf(mx[r], sc[ti][r]);
    #pragma unroll
    for (int off = 1; off < 16; off <<= 1)
      #pragma unroll
      for (int r = 0; r < 4; ++r) mx[r] = fmaxf(mx[r], __shfl_xor(mx[r], off));
    fx4 sm = (fx4){0.f, 0.f, 0.f, 0.f};
    #pragma unroll
    for (int ti = 0; ti < 5; ++ti)
      #pragma unroll
      for (int r = 0; r < 4; ++r) {
        float e = __expf(sc[ti][r] - mx[r]);
        sc[ti][r] = e; sm[r] += e;
      }
    #pragma unroll
    for (int off = 1; off < 16; off <<= 1)
      #pragma unroll
      for (int r = 0; r < 4; ++r) sm[r] += __shfl_xor(sm[r], off);
    #pragma unroll
    for (int ti = 0; ti < 5; ++ti)
      #pragma unroll
      for (int r = 0; r < 4; ++r)
        Ps[(qbase + qt * 16 + lg * 4 + r) * 104 + ti * 16 + lr] = f2bf(sc[ti][r] / sm[r]);
  }

  // ---- PV (swapped: A=V[d][s], B=P[q][s] -> D[d][q]) ----
  #pragma unroll
  for (int qt = 0; qt < 2; ++qt) {
    int q = qbase + qt * 16 + lr;
    fx4 o[4];
    #pragma unroll
    for (int dt = 0; dt < 4; ++dt) o[dt] = (fx4){0.f, 0.f, 0.f, 0.f};
    #pragma unroll
    for (int ks = 0; ks < 3; ++ks) {
      bfx8 bb = *(const bfx8*)&Ps[q * 104 + ks * 32 + lg * 8];
      #pragma unroll
      for (int dt = 0; dt < 4; ++dt) {
        bfx8 a = *(const bfx8*)&Vs[(dt * 16 + lr) * 104 + ks * 32 + lg * 8];
        o[dt] = __builtin_amdgcn_mfma_f32_16x16x32_bf16(a, bb, o[dt], 0, 0, 0);
      }
    }
    #pragma unroll
    for (int dt = 0; dt < 4; ++dt) {
      int db = dt * 16 + lg * 4;
      int pb = ((db >> 3) ^ (q & 7));
      U2 pk;
      #pragma unroll
      for (int r = 0; r < 4; ++r) pk.h[r] = f2bf(o[dt][r]);
      *(uint2*)&QO[q * 64 + (pb << 3) + (db & 7)] = pk.v;
    }
  }
  __syncthreads();

  const size_t aobase = (size_t)b * 524288 + (size_t)n0 * 512 + head * 64;
  #pragma unroll
  for (int j = 0; j < 4; ++j) {
    int idx = j * 256 + t;
    int row = idx >> 3, cs = (idx & 7) * 8;
    *(uint4*)(aoT + aobase + (size_t)row * 512 + cs) = *(const uint4*)&QO[row * 64 + cs];
  }
}

extern "C" void kernel_launch(void* const* d_in, const int* in_sizes, int n_in,
                              void* d_out, int out_size, void* d_ws, size_t ws_size,
                              hipStream_t stream) {
  const float* x      = (const float*)d_in[0];
  const float* ctx    = (const float*)d_in[1];
  const float* gn_w   = (const float*)d_in[2];
  const float* gn_b   = (const float*)d_in[3];
  const float* q_w    = (const float*)d_in[4];
  const float* q_b    = (const float*)d_in[5];
  const float* kv_w   = (const float*)d_in[6];
  const float* kv_b   = (const float*)d_in[7];
  const float* proj_w = (const float*)d_in[8];
  const float* proj_b = (const float*)d_in[9];
  float* out = (float*)d_out;

  u16* p = (u16*)d_ws;
  u16* qw_bf  = p; p += 262144;          // 512*512
  u16* kvw_bf = p; p += 786432;          // 1024*768
  u16* pjw_bf = p; p += 262144;          // 512*512
  u16* ctx_bf = p; p += 16 * 128 * 768;  // padded rows
  u16* hT     = p; p += 8388608;         // 16*1024*512
  u16* aoT    = p; p += 8388608;         // 16*1024*512 (was qT)
  u16* kvT_k  = p; p += 16 * 96 * 512;
  u16* kvV    = p; p += 16 * 512 * 80;
  float2* gpart  = (float2*)p; p += 1024 * 4;   // 1024 float2
  float2* gstats = (float2*)p; p += 128 * 4;    // 128 float2

  castw_kernel<<<256, 256, 0, stream>>>(q_w, qw_bf, 512, 65536);
  castw_kernel<<<768, 256, 0, stream>>>(kv_w, kvw_bf, 768, 196608);
  castw_kernel<<<256, 256, 0, stream>>>(proj_w, pjw_bf, 512, 65536);
  castctx_kernel<<<924, 256, 0, stream>>>(ctx, ctx_bf);

  gn_stats<<<1024, 256, 0, stream>>>(x, gpart);
  gn_stats2<<<1, 128, 0, stream>>>(gpart, gstats);
  gn_apply<<<1024, 256, 0, stream>>>(x, gn_w, gn_b, gstats, hT);

  // KV: A=ctx [128pad][768], B=kv_w [1024][768] -> K^T + V
  gemm2_kernel<1><<<dim3(8, 1, B_), 256, 0, stream>>>(
      ctx_bf, kvw_bf, kv_b, nullptr, nullptr, kvT_k, kvV, 768, (size_t)128 * 768);

  // fused Q-GEMM + attention
  qattn_kernel<<<dim3(8, HEADS_, B_), 256, 0, stream>>>(hT, qw_bf, q_b, kvT_k, kvV, aoT);

  // proj: A=aoT [1024][512], B=proj_w [512][512] -> f32 out + residual
  gemm2_kernel<2><<<dim3(4, 8, B_), 256, 0, stream>>>(
      aoT, pjw_bf, proj_b, x, out, nullptr, nullptr, 512, (size_t)1024 * 512);
}